// Round 2
// baseline (429.920 us; speedup 1.0000x reference)
//
#include <hip/hip_runtime.h>
#include <cmath>

// Problem constants: B=32, N=512, IN=128, HID=32, HEADS=4, OUT=128
// ALL float tensors are fp32 (reference is jnp.float32); graph is int32; out fp32.
// Workspace layout (floats): fA[2097152] fB[2097152] fC[2097152]
//   e0s[65536] e0d[65536] e1s[16384] e1d[16384]  => 25.8 MB total
// Stage graph: K1 fA<-x@W0 ; K2 e0 ; K3 fB<-elu(GAT0) ; K4 fA<-fB@W1 ;
//   K5 e1 ; K6 fC<-GAT1 ; K7 fB<-ln1(x||fC)@lin_W ; K8 out<-tail(fB)

__device__ __forceinline__ float gelu_f(float v) {
    return 0.5f * v * (1.0f + erff(v * 0.70710678118654752f));
}

// ---------------- Y[R,128] = X[R,128] @ W[128,128] (fp32) --------------------
__global__ __launch_bounds__(256) void gemm128(const float* __restrict__ X,
                                               const float* __restrict__ W,
                                               float* __restrict__ Y) {
    __shared__ float xs[32 * 132];   // +4 pad
    __shared__ float wl[64 * 128];   // one k-half of W
    const int tid = threadIdx.x;
    const int row0 = blockIdx.x * 32;
    {   // stage 32 input rows, float4 loads
        const float4* X4 = (const float4*)(X + row0 * 128);
        for (int i = tid; i < 32 * 32; i += 256) {
            int r = i >> 5, f4 = i & 31;
            float4 v = X4[r * 32 + f4];
            xs[r * 132 + f4 * 4 + 0] = v.x;
            xs[r * 132 + f4 * 4 + 1] = v.y;
            xs[r * 132 + f4 * 4 + 2] = v.z;
            xs[r * 132 + f4 * 4 + 3] = v.w;
        }
    }
    const int r = tid >> 3, t = tid & 7;      // 32 rows x 8 col-groups
    float4 acc[4];
#pragma unroll
    for (int j = 0; j < 4; j++) acc[j] = make_float4(0.f, 0.f, 0.f, 0.f);
    for (int half = 0; half < 2; half++) {
        __syncthreads();
        {
            float4* wl4 = (float4*)wl;
            const float4* W4 = (const float4*)(W + half * 8192);
            for (int i = tid; i < 2048; i += 256) wl4[i] = W4[i];
        }
        __syncthreads();
        const float4* wl4 = (const float4*)wl;
        for (int k = 0; k < 64; k++) {
            float xv = xs[r * 132 + half * 64 + k];
#pragma unroll
            for (int j = 0; j < 4; j++) {          // c = 4t + 32j
                float4 wv = wl4[k * 32 + t + 8 * j];
                acc[j].x = fmaf(xv, wv.x, acc[j].x);
                acc[j].y = fmaf(xv, wv.y, acc[j].y);
                acc[j].z = fmaf(xv, wv.z, acc[j].z);
                acc[j].w = fmaf(xv, wv.w, acc[j].w);
            }
        }
    }
    float4* Y4 = (float4*)Y;
#pragma unroll
    for (int j = 0; j < 4; j++) Y4[(row0 + r) * 32 + t + 8 * j] = acc[j];
}

// ------------- e_src/e_dst for GAT0: [B][H][N], 32-dot per (b,h,n) -----------
__global__ __launch_bounds__(256) void attn_coef0(const float* __restrict__ H,
        const float* __restrict__ a_s, const float* __restrict__ a_d,
        float* __restrict__ es, float* __restrict__ ed) {
    int idx = blockIdx.x * 256 + threadIdx.x;        // 65536 = B*H*N
    int rem = idx & 2047;
    int h = rem >> 9;
    const float* hr = H + (idx >> 11) * 65536 + (rem & 511) * 128 + h * 32;
    float s = 0.f, d = 0.f;
#pragma unroll 8
    for (int k = 0; k < 32; k++) {
        float v = hr[k];
        s = fmaf(v, a_s[h * 32 + k], s);
        d = fmaf(v, a_d[h * 32 + k], d);
    }
    es[idx] = s; ed[idx] = d;                        // idx == (b*4+h)*512+n
}

// ------------- e_src/e_dst for GAT1: [B][N], 128-dot per (b,n) ---------------
__global__ __launch_bounds__(256) void attn_coef1(const float* __restrict__ H,
        const float* __restrict__ a_s, const float* __restrict__ a_d,
        float* __restrict__ es, float* __restrict__ ed) {
    int idx = blockIdx.x * 256 + threadIdx.x;        // 16384 = B*N
    const float* hr = H + idx * 128;
    float s = 0.f, d = 0.f;
#pragma unroll 8
    for (int k = 0; k < 128; k++) {
        float v = hr[k];
        s = fmaf(v, a_s[k], s);
        d = fmaf(v, a_d[k], d);
    }
    es[idx] = s; ed[idx] = d;
}

// ----- GAT0 attention+aggregate+ELU: O[b,n,h*32+d], 4 heads, single pass -----
__global__ __launch_bounds__(256) void gat0_attn(const float* __restrict__ H,
        const float* __restrict__ es0, const float* __restrict__ ed0,
        const int* __restrict__ graph, float* __restrict__ O) {
    __shared__ float hs[64 * 128];    // 32KB: m-chunk of h0[b]
    __shared__ float wts[32 * 256];   // 32KB: [n][hh][m^n] softmax numerators
    const int tid = threadIdx.x;
    const int b = blockIdx.y, n0 = blockIdx.x * 32;
    const int n = tid >> 3, q = tid & 7;             // 32 n x 8 col-groups
    float4 acc[4];
#pragma unroll
    for (int j = 0; j < 4; j++) acc[j] = make_float4(0.f, 0.f, 0.f, 0.f);
    float dsum[4] = {0.f, 0.f, 0.f, 0.f};
    for (int mc = 0; mc < 512; mc += 64) {
        __syncthreads();
        {
            float4* hs4w = (float4*)hs;
            const float4* H4 = (const float4*)(H + (b * 512 + mc) * 128);
            for (int i = tid; i < 2048; i += 256) hs4w[i] = H4[i];
        }
        for (int i = tid; i < 8192; i += 256) {      // i = nn*256 + hh*64 + m
            int nn = i >> 8, hh = (i >> 6) & 3, m = i & 63;
            int ng = n0 + nn, mg = mc + m;
            int g = graph[(b * 512 + ng) * 512 + mg];
            float e = es0[(b * 4 + hh) * 512 + ng] + ed0[(b * 4 + hh) * 512 + mg];
            e = e > 0.f ? e : 0.2f * e;              // leaky_relu 0.2
            wts[nn * 256 + hh * 64 + (m ^ nn)] = (g > 0 || mg == ng) ? __expf(e) : 0.f;
        }
        __syncthreads();
        const float4* hs4 = (const float4*)hs;
        for (int m = 0; m < 64; m++) {
#pragma unroll
            for (int hh = 0; hh < 4; hh++) {         // c = 32hh + 4q
                float w = wts[n * 256 + hh * 64 + (m ^ n)];
                dsum[hh] += w;
                float4 hv = hs4[m * 32 + hh * 8 + q];
                acc[hh].x = fmaf(w, hv.x, acc[hh].x);
                acc[hh].y = fmaf(w, hv.y, acc[hh].y);
                acc[hh].z = fmaf(w, hv.z, acc[hh].z);
                acc[hh].w = fmaf(w, hv.w, acc[hh].w);
            }
        }
    }
    const int row = b * 512 + n0 + n;
    float4* O4 = (float4*)O;
#pragma unroll
    for (int hh = 0; hh < 4; hh++) {
        float inv = 1.0f / dsum[hh];
        float4 v = acc[hh];
        v.x *= inv; v.y *= inv; v.z *= inv; v.w *= inv;
        v.x = v.x > 0.f ? v.x : expm1f(v.x);         // ELU
        v.y = v.y > 0.f ? v.y : expm1f(v.y);
        v.z = v.z > 0.f ? v.z : expm1f(v.z);
        v.w = v.w > 0.f ? v.w : expm1f(v.w);
        O4[row * 32 + hh * 8 + q] = v;
    }
}

// -------- GAT1 attention+aggregate (1 head, D=128, no activation) ------------
__global__ __launch_bounds__(256) void gat1_attn(const float* __restrict__ H,
        const float* __restrict__ es1, const float* __restrict__ ed1,
        const int* __restrict__ graph, float* __restrict__ O) {
    __shared__ float hs[64 * 128];
    __shared__ float wts[32 * 64];
    const int tid = threadIdx.x;
    const int b = blockIdx.y, n0 = blockIdx.x * 32;
    const int n = tid >> 3, q = tid & 7;
    float4 acc[4];
#pragma unroll
    for (int j = 0; j < 4; j++) acc[j] = make_float4(0.f, 0.f, 0.f, 0.f);
    float dsum = 0.f;
    for (int mc = 0; mc < 512; mc += 64) {
        __syncthreads();
        {
            float4* hs4w = (float4*)hs;
            const float4* H4 = (const float4*)(H + (b * 512 + mc) * 128);
            for (int i = tid; i < 2048; i += 256) hs4w[i] = H4[i];
        }
        for (int i = tid; i < 2048; i += 256) {      // i = nn*64 + m
            int nn = i >> 6, m = i & 63;
            int ng = n0 + nn, mg = mc + m;
            int g = graph[(b * 512 + ng) * 512 + mg];
            float e = es1[b * 512 + ng] + ed1[b * 512 + mg];
            e = e > 0.f ? e : 0.2f * e;
            wts[nn * 64 + (m ^ nn)] = (g > 0 || mg == ng) ? __expf(e) : 0.f;
        }
        __syncthreads();
        const float4* hs4 = (const float4*)hs;
        for (int m = 0; m < 64; m++) {
            float w = wts[n * 64 + (m ^ n)];
            dsum += w;
#pragma unroll
            for (int j = 0; j < 4; j++) {            // c = 32j + 4q
                float4 hv = hs4[m * 32 + j * 8 + q];
                acc[j].x = fmaf(w, hv.x, acc[j].x);
                acc[j].y = fmaf(w, hv.y, acc[j].y);
                acc[j].z = fmaf(w, hv.z, acc[j].z);
                acc[j].w = fmaf(w, hv.w, acc[j].w);
            }
        }
    }
    const int row = b * 512 + n0 + n;
    float inv = 1.0f / dsum;
    float4* O4 = (float4*)O;
#pragma unroll
    for (int j = 0; j < 4; j++) {
        float4 v = acc[j];
        v.x *= inv; v.y *= inv; v.z *= inv; v.w *= inv;
        O4[row * 32 + j * 8 + q] = v;
    }
}

// ------- ln1 over concat(x[128], g1[128]) then O = y @ lin_W + lin_b ---------
__global__ __launch_bounds__(256) void ln1_linear(const float* __restrict__ x,
        const float* __restrict__ G, const float* __restrict__ g1, const float* __restrict__ b1,
        const float* __restrict__ LW, const float* __restrict__ LB,
        float* __restrict__ O) {
    __shared__ float yrow[16 * 258];  // +2 pad
    __shared__ float lwf[8192];       // k-quarter of lin_W
    __shared__ float2 red[256];
    __shared__ float2 mvs[16];
    const int tid = threadIdx.x;
    const int row0 = blockIdx.x * 16;
    const int r = tid >> 4, t = tid & 15;
    const int row = row0 + r;
    float s = 0.f, ss = 0.f;
#pragma unroll
    for (int i4 = 0; i4 < 4; i4++) {
        int k = t * 16 + i4 * 4;
        float4 v = (k < 128) ? ((const float4*)(x + row * 128))[k >> 2]
                             : ((const float4*)(G + row * 128))[(k - 128) >> 2];
        yrow[r * 258 + k + 0] = v.x; yrow[r * 258 + k + 1] = v.y;
        yrow[r * 258 + k + 2] = v.z; yrow[r * 258 + k + 3] = v.w;
        s += v.x + v.y + v.z + v.w;
        ss += v.x * v.x + v.y * v.y + v.z * v.z + v.w * v.w;
    }
    red[tid] = make_float2(s, ss);
    __syncthreads();
    if (t == 0) {
        float S = 0.f, SS = 0.f;
        for (int i = 0; i < 16; i++) { S += red[r * 16 + i].x; SS += red[r * 16 + i].y; }
        float mu = S * (1.f / 256.f);
        float var = SS * (1.f / 256.f) - mu * mu;
        mvs[r] = make_float2(mu, rsqrtf(var + 1e-5f));
    }
    __syncthreads();
    {
        float mu = mvs[r].x, rstd = mvs[r].y;
#pragma unroll
        for (int i = 0; i < 16; i++) {
            int k = t * 16 + i;
            yrow[r * 258 + k] = (yrow[r * 258 + k] - mu) * rstd * g1[k] + b1[k];
        }
    }
    float4 acc[2];
    acc[0] = make_float4(0.f, 0.f, 0.f, 0.f);
    acc[1] = make_float4(0.f, 0.f, 0.f, 0.f);
    for (int qr = 0; qr < 4; qr++) {
        __syncthreads();
        {
            float4* l4 = (float4*)lwf;
            const float4* W4 = (const float4*)(LW + qr * 8192);
            for (int i = tid; i < 2048; i += 256) l4[i] = W4[i];
        }
        __syncthreads();
        const float4* w4 = (const float4*)lwf;
        for (int k = 0; k < 64; k++) {
            float yv = yrow[r * 258 + qr * 64 + k];
#pragma unroll
            for (int j = 0; j < 2; j++) {            // c = 4t + 64j
                float4 wv = w4[k * 32 + t + 16 * j];
                acc[j].x = fmaf(yv, wv.x, acc[j].x);
                acc[j].y = fmaf(yv, wv.y, acc[j].y);
                acc[j].z = fmaf(yv, wv.z, acc[j].z);
                acc[j].w = fmaf(yv, wv.w, acc[j].w);
            }
        }
    }
    float4* O4 = (float4*)O;
#pragma unroll
    for (int j = 0; j < 2; j++) {
        int c = 4 * t + 64 * j;
        acc[j].x += LB[c + 0]; acc[j].y += LB[c + 1];
        acc[j].z += LB[c + 2]; acc[j].w += LB[c + 3];
        O4[row * 32 + t + 16 * j] = acc[j];
    }
}

// --- tail: enc=gelu(m@W0+b0)@W1+b1 ; ln2(m+enc) ; gelu(@oh_W+oh_b) ; ln3 -----
__global__ __launch_bounds__(256) void tail_fused(const float* __restrict__ M,
        const float* __restrict__ W0g, const float* __restrict__ B0g,
        const float* __restrict__ W1g, const float* __restrict__ B1g,
        const float* __restrict__ g2, const float* __restrict__ b2,
        const float* __restrict__ Wog, const float* __restrict__ Bog,
        const float* __restrict__ g3, const float* __restrict__ b3,
        float* __restrict__ out) {
    __shared__ float wh[8192];        // k-half of current weight
    __shared__ float mrow[16 * 132];
    __shared__ float trow[16 * 132];
    __shared__ float rrow[16 * 132];
    __shared__ float2 red[256];
    __shared__ float2 mvs[16];
    const int tid = threadIdx.x;
    const int row0 = blockIdx.x * 16;
    const int r = tid >> 4, t = tid & 15;
    const int row = row0 + r;
    {
        const float4* M4 = (const float4*)(M + row0 * 128);
        for (int i = tid; i < 512; i += 256) {
            int rr_ = i >> 5, f4 = i & 31;
            ((float4*)(mrow + rr_ * 132))[f4] = M4[rr_ * 32 + f4];
        }
    }
    // phase 1: trow = gelu(m @ me_W0 + b0)
    float4 acc[2];
#pragma unroll
    for (int j = 0; j < 2; j++) {
        int c = 4 * t + 64 * j;
        acc[j] = make_float4(B0g[c], B0g[c + 1], B0g[c + 2], B0g[c + 3]);
    }
    for (int half = 0; half < 2; half++) {
        __syncthreads();
        {
            float4* w4w = (float4*)wh;
            const float4* W4 = (const float4*)(W0g + half * 8192);
            for (int i = tid; i < 2048; i += 256) w4w[i] = W4[i];
        }
        __syncthreads();
        const float4* w4 = (const float4*)wh;
        for (int k = 0; k < 64; k++) {
            float mv = mrow[r * 132 + half * 64 + k];
#pragma unroll
            for (int j = 0; j < 2; j++) {
                float4 wv = w4[k * 32 + t + 16 * j];
                acc[j].x = fmaf(mv, wv.x, acc[j].x);
                acc[j].y = fmaf(mv, wv.y, acc[j].y);
                acc[j].z = fmaf(mv, wv.z, acc[j].z);
                acc[j].w = fmaf(mv, wv.w, acc[j].w);
            }
        }
    }
    {
        float4* t4 = (float4*)trow;
#pragma unroll
        for (int j = 0; j < 2; j++) {
            float4 v;
            v.x = gelu_f(acc[j].x); v.y = gelu_f(acc[j].y);
            v.z = gelu_f(acc[j].z); v.w = gelu_f(acc[j].w);
            t4[r * 33 + t + 16 * j] = v;
        }
    }
    // phase 2: u = trow @ me_W1 + b1 ; rr = m + u ; ln2 -> rrow
    float4 acc2[2];
#pragma unroll
    for (int j = 0; j < 2; j++) {
        int c = 4 * t + 64 * j;
        acc2[j] = make_float4(B1g[c], B1g[c + 1], B1g[c + 2], B1g[c + 3]);
    }
    for (int half = 0; half < 2; half++) {
        __syncthreads();
        {
            float4* w4w = (float4*)wh;
            const float4* W4 = (const float4*)(W1g + half * 8192);
            for (int i = tid; i < 2048; i += 256) w4w[i] = W4[i];
        }
        __syncthreads();
        const float4* w4 = (const float4*)wh;
        for (int k = 0; k < 64; k++) {
            float tv = trow[r * 132 + half * 64 + k];
#pragma unroll
            for (int j = 0; j < 2; j++) {
                float4 wv = w4[k * 32 + t + 16 * j];
                acc2[j].x = fmaf(tv, wv.x, acc2[j].x);
                acc2[j].y = fmaf(tv, wv.y, acc2[j].y);
                acc2[j].z = fmaf(tv, wv.z, acc2[j].z);
                acc2[j].w = fmaf(tv, wv.w, acc2[j].w);
            }
        }
    }
    float rr[8];
    {
        float s = 0.f, ss = 0.f;
#pragma unroll
        for (int j = 0; j < 2; j++) {
            int c = 4 * t + 64 * j;
            float v0 = mrow[r * 132 + c + 0] + acc2[j].x;
            float v1 = mrow[r * 132 + c + 1] + acc2[j].y;
            float v2 = mrow[r * 132 + c + 2] + acc2[j].z;
            float v3 = mrow[r * 132 + c + 3] + acc2[j].w;
            rr[j * 4 + 0] = v0; rr[j * 4 + 1] = v1; rr[j * 4 + 2] = v2; rr[j * 4 + 3] = v3;
            s += v0 + v1 + v2 + v3;
            ss += v0 * v0 + v1 * v1 + v2 * v2 + v3 * v3;
        }
        red[tid] = make_float2(s, ss);
    }
    __syncthreads();
    if (t == 0) {
        float S = 0.f, SS = 0.f;
        for (int i = 0; i < 16; i++) { S += red[r * 16 + i].x; SS += red[r * 16 + i].y; }
        float mu = S * (1.f / 128.f);
        float var = SS * (1.f / 128.f) - mu * mu;
        mvs[r] = make_float2(mu, rsqrtf(var + 1e-5f));
    }
    __syncthreads();
    {
        float mu = mvs[r].x, rstd = mvs[r].y;
        float4* r4 = (float4*)rrow;
#pragma unroll
        for (int j = 0; j < 2; j++) {
            int c = 4 * t + 64 * j;
            float4 v;
            v.x = (rr[j * 4 + 0] - mu) * rstd * g2[c + 0] + b2[c + 0];
            v.y = (rr[j * 4 + 1] - mu) * rstd * g2[c + 1] + b2[c + 1];
            v.z = (rr[j * 4 + 2] - mu) * rstd * g2[c + 2] + b2[c + 2];
            v.w = (rr[j * 4 + 3] - mu) * rstd * g2[c + 3] + b2[c + 3];
            r4[r * 33 + t + 16 * j] = v;
        }
    }
    // phase 3: v = gelu(rrow @ oh_W + oh_b) ; ln3 ; store fp32
    float4 acc3[2];
#pragma unroll
    for (int j = 0; j < 2; j++) {
        int c = 4 * t + 64 * j;
        acc3[j] = make_float4(Bog[c], Bog[c + 1], Bog[c + 2], Bog[c + 3]);
    }
    for (int half = 0; half < 2; half++) {
        __syncthreads();
        {
            float4* w4w = (float4*)wh;
            const float4* W4 = (const float4*)(Wog + half * 8192);
            for (int i = tid; i < 2048; i += 256) w4w[i] = W4[i];
        }
        __syncthreads();
        const float4* w4 = (const float4*)wh;
        for (int k = 0; k < 64; k++) {
            float rv = rrow[r * 132 + half * 64 + k];
#pragma unroll
            for (int j = 0; j < 2; j++) {
                float4 wv = w4[k * 32 + t + 16 * j];
                acc3[j].x = fmaf(rv, wv.x, acc3[j].x);
                acc3[j].y = fmaf(rv, wv.y, acc3[j].y);
                acc3[j].z = fmaf(rv, wv.z, acc3[j].z);
                acc3[j].w = fmaf(rv, wv.w, acc3[j].w);
            }
        }
    }
    float vv[8];
    {
        float s = 0.f, ss = 0.f;
        float a[8] = {acc3[0].x, acc3[0].y, acc3[0].z, acc3[0].w,
                      acc3[1].x, acc3[1].y, acc3[1].z, acc3[1].w};
#pragma unroll
        for (int i = 0; i < 8; i++) {
            float g = gelu_f(a[i]);
            vv[i] = g; s += g; ss += g * g;
        }
        red[tid] = make_float2(s, ss);
    }
    __syncthreads();
    if (t == 0) {
        float S = 0.f, SS = 0.f;
        for (int i = 0; i < 16; i++) { S += red[r * 16 + i].x; SS += red[r * 16 + i].y; }
        float mu = S * (1.f / 128.f);
        float var = SS * (1.f / 128.f) - mu * mu;
        mvs[r] = make_float2(mu, rsqrtf(var + 1e-5f));
    }
    __syncthreads();
    {
        float mu = mvs[r].x, rstd = mvs[r].y;
        float4* o4 = (float4*)out;
#pragma unroll
        for (int j = 0; j < 2; j++) {
            int c = 4 * t + 64 * j;
            float4 v;
            v.x = (vv[j * 4 + 0] - mu) * rstd * g3[c + 0] + b3[c + 0];
            v.y = (vv[j * 4 + 1] - mu) * rstd * g3[c + 1] + b3[c + 1];
            v.z = (vv[j * 4 + 2] - mu) * rstd * g3[c + 2] + b3[c + 2];
            v.w = (vv[j * 4 + 3] - mu) * rstd * g3[c + 3] + b3[c + 3];
            o4[row * 32 + t + 16 * j] = v;
        }
    }
}

extern "C" void kernel_launch(void* const* d_in, const int* in_sizes, int n_in,
                              void* d_out, int out_size, void* d_ws, size_t ws_size,
                              hipStream_t stream) {
    const float* x      = (const float*)d_in[0];
    const int*   graph  = (const int*)d_in[1];
    const float* W0     = (const float*)d_in[2];
    const float* a_src0 = (const float*)d_in[3];
    const float* a_dst0 = (const float*)d_in[4];
    const float* W1     = (const float*)d_in[5];
    const float* a_src1 = (const float*)d_in[6];
    const float* a_dst1 = (const float*)d_in[7];
    const float* ln1_g  = (const float*)d_in[8];
    const float* ln1_b  = (const float*)d_in[9];
    const float* lin_W  = (const float*)d_in[10];
    const float* lin_b  = (const float*)d_in[11];
    const float* me_W0  = (const float*)d_in[12];
    const float* me_b0  = (const float*)d_in[13];
    const float* me_W1  = (const float*)d_in[14];
    const float* me_b1  = (const float*)d_in[15];
    const float* ln2_g  = (const float*)d_in[16];
    const float* ln2_b  = (const float*)d_in[17];
    const float* oh_W   = (const float*)d_in[18];
    const float* oh_b   = (const float*)d_in[19];
    const float* ln3_g  = (const float*)d_in[20];
    const float* ln3_b  = (const float*)d_in[21];
    float* out = (float*)d_out;

    float* ws  = (float*)d_ws;
    float* fA  = ws;                  // 2097152
    float* fB  = ws + 2097152;        // 2097152
    float* fC  = ws + 4194304;        // 2097152
    float* e0s = ws + 6291456;        // 65536
    float* e0d = e0s + 65536;         // 65536
    float* e1s = e0d + 65536;         // 16384
    float* e1d = e1s + 16384;         // 16384

    gemm128<<<512, 256, 0, stream>>>(x, W0, fA);                               // h0
    attn_coef0<<<256, 256, 0, stream>>>(fA, a_src0, a_dst0, e0s, e0d);
    gat0_attn<<<dim3(16, 32), 256, 0, stream>>>(fA, e0s, e0d, graph, fB);      // m = elu(gat0)
    gemm128<<<512, 256, 0, stream>>>(fB, W1, fA);                              // h1
    attn_coef1<<<64, 256, 0, stream>>>(fA, a_src1, a_dst1, e1s, e1d);
    gat1_attn<<<dim3(16, 32), 256, 0, stream>>>(fA, e1s, e1d, graph, fC);      // g1
    ln1_linear<<<1024, 256, 0, stream>>>(x, fC, ln1_g, ln1_b, lin_W, lin_b, fB);
    tail_fused<<<1024, 256, 0, stream>>>(fB, me_W0, me_b0, me_W1, me_b1,
                                         ln2_g, ln2_b, oh_W, oh_b, ln3_g, ln3_b, out);
}

// Round 3
// 315.464 us; speedup vs baseline: 1.3628x; 1.3628x over previous
//
#include <hip/hip_runtime.h>
#include <cmath>

// Problem constants: B=32, N=512, IN=128, HID=32, HEADS=4, OUT=128
// All float tensors fp32; graph int32; out fp32.
// ws (floats): fA[2M] fB[2M] Ht[1M floats = 2M ushort bf16] e0s[64K] e0d[64K] e1s[16K] e1d[16K]
// Stages: K1 fA<-x@W0 (+Ht bf16 transposed) ; K2 e0 ; K3 fB<-elu(GAT0,MFMA) ;
//   K4 fA<-fB@W1 (+Ht) ; K5 e1 ; K6 fA<-GAT1(MFMA) ; K7 fB<-ln1(x||fA)@lin_W ; K8 out<-tail(fB)

typedef unsigned short ushort_t;
typedef __attribute__((ext_vector_type(8))) short short8;
typedef __attribute__((ext_vector_type(4))) float f32x4;

__device__ __forceinline__ float gelu_f(float v) {
    return 0.5f * v * (1.0f + erff(v * 0.70710678118654752f));
}

__device__ __forceinline__ ushort_t f2bf(float x) {
    union { float f; unsigned u; } v; v.f = x;
    unsigned r = (v.u + 0x7FFFu + ((v.u >> 16) & 1u)) >> 16;
    return (ushort_t)r;
}

// ------- Y[R,128] = X[R,128] @ W[128,128] fp32 ; also Ht[b][c][m] bf16 -------
__global__ __launch_bounds__(256) void gemm128t(const float* __restrict__ X,
                                                const float* __restrict__ W,
                                                float* __restrict__ Y,
                                                ushort_t* __restrict__ Ht) {
    __shared__ float xs[32 * 132];
    __shared__ float wl[64 * 128];
    const int tid = threadIdx.x;
    const int row0 = blockIdx.x * 32;
    {
        const float4* X4 = (const float4*)(X + row0 * 128);
        for (int i = tid; i < 32 * 32; i += 256) {
            int r = i >> 5, f4 = i & 31;
            float4 v = X4[r * 32 + f4];
            xs[r * 132 + f4 * 4 + 0] = v.x;
            xs[r * 132 + f4 * 4 + 1] = v.y;
            xs[r * 132 + f4 * 4 + 2] = v.z;
            xs[r * 132 + f4 * 4 + 3] = v.w;
        }
    }
    const int r = tid >> 3, t = tid & 7;
    float4 acc[4];
#pragma unroll
    for (int j = 0; j < 4; j++) acc[j] = make_float4(0.f, 0.f, 0.f, 0.f);
    for (int half = 0; half < 2; half++) {
        __syncthreads();
        {
            float4* wl4 = (float4*)wl;
            const float4* W4 = (const float4*)(W + half * 8192);
            for (int i = tid; i < 2048; i += 256) wl4[i] = W4[i];
        }
        __syncthreads();
        const float4* wl4 = (const float4*)wl;
        for (int k = 0; k < 64; k++) {
            float xv = xs[r * 132 + half * 64 + k];
#pragma unroll
            for (int j = 0; j < 4; j++) {
                float4 wv = wl4[k * 32 + t + 8 * j];
                acc[j].x = fmaf(xv, wv.x, acc[j].x);
                acc[j].y = fmaf(xv, wv.y, acc[j].y);
                acc[j].z = fmaf(xv, wv.z, acc[j].z);
                acc[j].w = fmaf(xv, wv.w, acc[j].w);
            }
        }
    }
    const int row = row0 + r;
    float4* Y4 = (float4*)Y;
#pragma unroll
    for (int j = 0; j < 4; j++) Y4[row * 32 + t + 8 * j] = acc[j];
    // bf16 transposed copy: Ht[(b*128+c)*512 + m]
    const int b = row >> 9, m = row & 511;
    ushort_t* Hb = Ht + b * 65536 + m;
#pragma unroll
    for (int j = 0; j < 4; j++) {
        int c = 4 * t + 32 * j;
        Hb[(c + 0) * 512] = f2bf(acc[j].x);
        Hb[(c + 1) * 512] = f2bf(acc[j].y);
        Hb[(c + 2) * 512] = f2bf(acc[j].z);
        Hb[(c + 3) * 512] = f2bf(acc[j].w);
    }
}

// ------------- e_src/e_dst for GAT0: [B][H][N], 32-dot per (b,h,n) -----------
__global__ __launch_bounds__(256) void attn_coef0(const float* __restrict__ H,
        const float* __restrict__ a_s, const float* __restrict__ a_d,
        float* __restrict__ es, float* __restrict__ ed) {
    int idx = blockIdx.x * 256 + threadIdx.x;        // 65536 = B*H*N
    int rem = idx & 2047;
    int h = rem >> 9;
    const float* hr = H + (idx >> 11) * 65536 + (rem & 511) * 128 + h * 32;
    float s = 0.f, d = 0.f;
#pragma unroll 8
    for (int k = 0; k < 32; k++) {
        float v = hr[k];
        s = fmaf(v, a_s[h * 32 + k], s);
        d = fmaf(v, a_d[h * 32 + k], d);
    }
    es[idx] = s; ed[idx] = d;                        // idx == (b*4+h)*512+n
}

// ------------- e_src/e_dst for GAT1: [B][N], 128-dot per (b,n) ---------------
__global__ __launch_bounds__(256) void attn_coef1(const float* __restrict__ H,
        const float* __restrict__ a_s, const float* __restrict__ a_d,
        float* __restrict__ es, float* __restrict__ ed) {
    int idx = blockIdx.x * 256 + threadIdx.x;        // 16384 = B*N
    const float* hr = H + idx * 128;
    float s = 0.f, d = 0.f;
#pragma unroll 8
    for (int k = 0; k < 128; k++) {
        float v = hr[k];
        s = fmaf(v, a_s[k], s);
        d = fmaf(v, a_d[k], d);
    }
    es[idx] = s; ed[idx] = d;
}

// --------- GAT0 via MFMA: O[b,n,h*32+d] = softmax(P) @ H, then ELU -----------
// Wave w = head. A = P_h[32n x 64m] bf16 (LDS, computed), B = Ht chunk bf16.
__global__ __launch_bounds__(256) void gat0_mfma(const ushort_t* __restrict__ Ht,
        const float* __restrict__ es0, const float* __restrict__ ed0,
        const int* __restrict__ graph, float* __restrict__ O) {
    __shared__ ushort_t hsb[128 * 72];   // [c][m] bf16, stride 72 (16B-aligned rows)
    __shared__ ushort_t ps[4 * 32 * 72]; // [hh][nn][m] bf16
    __shared__ float eds[4 * 512];
    __shared__ float ess[4 * 32];
    const int tid = threadIdx.x;
    const int b = blockIdx.y, n0 = blockIdx.x * 32;
    const int lane = tid & 63, wv = tid >> 6;        // wv = head
    const int quad = lane >> 4, lid = lane & 15;
    for (int i = tid; i < 2048; i += 256) eds[i] = ed0[b * 2048 + i];
    if (tid < 128) ess[tid] = es0[b * 2048 + (tid >> 5) * 512 + n0 + (tid & 31)];
    const short8 onesf = {0x3F80, 0x3F80, 0x3F80, 0x3F80, 0x3F80, 0x3F80, 0x3F80, 0x3F80};
    f32x4 acc[2][2], dsf[2];
#pragma unroll
    for (int a = 0; a < 2; a++) {
        dsf[a] = (f32x4){0.f, 0.f, 0.f, 0.f};
#pragma unroll
        for (int c = 0; c < 2; c++) acc[a][c] = (f32x4){0.f, 0.f, 0.f, 0.f};
    }
    for (int mc = 0; mc < 512; mc += 64) {
        __syncthreads();
        {   // stage Ht chunk [128c][64m]
            const ushort_t* src = Ht + b * 65536 + mc;
            for (int u = tid; u < 1024; u += 256) {
                int c = u >> 3, ms = (u & 7) * 8;
                *(short8*)&hsb[c * 72 + ms] = *(const short8*)&src[c * 512 + ms];
            }
        }
        // P: 1024 groups of 8 m; g = nn*32? -> nn=g>>5, hh=(g>>3)&3, mg=g&7
        for (int g = tid; g < 1024; g += 256) {
            int nn = g >> 5, hh = (g >> 3) & 3, mg = g & 7;
            int ng = n0 + nn, mbase = mc + mg * 8;
            const int* grow = graph + (b * 512 + ng) * 512 + mbase;
            int4 ga = *(const int4*)grow;
            int4 gb = *(const int4*)(grow + 4);
            float es_v = ess[hh * 32 + nn];
            int gv[8] = {ga.x, ga.y, ga.z, ga.w, gb.x, gb.y, gb.z, gb.w};
            short8 pk;
#pragma unroll
            for (int j = 0; j < 8; j++) {
                float e = es_v + eds[hh * 512 + mbase + j];
                e = e > 0.f ? e : 0.2f * e;
                bool keep = (gv[j] > 0) | ((mbase + j) == ng);
                float w = keep ? __expf(e) : 0.f;
                pk[j] = (short)f2bf(w);
            }
            *(short8*)&ps[(hh * 32 + nn) * 72 + mg * 8] = pk;
        }
        __syncthreads();
#pragma unroll
        for (int kc = 0; kc < 2; kc++) {
            short8 af[2], bfr[2];
#pragma unroll
            for (int nh = 0; nh < 2; nh++)
                af[nh] = *(const short8*)&ps[(wv * 32 + nh * 16 + lid) * 72 + kc * 32 + quad * 8];
#pragma unroll
            for (int ch = 0; ch < 2; ch++)
                bfr[ch] = *(const short8*)&hsb[(wv * 32 + ch * 16 + lid) * 72 + kc * 32 + quad * 8];
#pragma unroll
            for (int nh = 0; nh < 2; nh++) {
#pragma unroll
                for (int ch = 0; ch < 2; ch++)
                    acc[nh][ch] = __builtin_amdgcn_mfma_f32_16x16x32_bf16(af[nh], bfr[ch], acc[nh][ch], 0, 0, 0);
                dsf[nh] = __builtin_amdgcn_mfma_f32_16x16x32_bf16(af[nh], onesf, dsf[nh], 0, 0, 0);
            }
        }
    }
#pragma unroll
    for (int nh = 0; nh < 2; nh++) {
#pragma unroll
        for (int reg = 0; reg < 4; reg++) {
            float inv = 1.0f / dsf[nh][reg];
            int row = b * 512 + n0 + nh * 16 + quad * 4 + reg;
#pragma unroll
            for (int ch = 0; ch < 2; ch++) {
                float v = acc[nh][ch][reg] * inv;
                v = v > 0.f ? v : expm1f(v);         // ELU
                O[row * 128 + wv * 32 + ch * 16 + lid] = v;
            }
        }
    }
}

// --------- GAT1 via MFMA: O[b,n,c] 1 head D=128; wave w = c-range -----------
__global__ __launch_bounds__(256) void gat1_mfma(const ushort_t* __restrict__ Ht,
        const float* __restrict__ es1, const float* __restrict__ ed1,
        const int* __restrict__ graph, float* __restrict__ O) {
    __shared__ ushort_t hsb[128 * 72];
    __shared__ ushort_t ps[32 * 72];
    __shared__ float eds[512];
    __shared__ float ess[32];
    const int tid = threadIdx.x;
    const int b = blockIdx.y, n0 = blockIdx.x * 32;
    const int lane = tid & 63, wv = tid >> 6;        // wv = col-block (32 c each)
    const int quad = lane >> 4, lid = lane & 15;
    for (int i = tid; i < 512; i += 256) eds[i] = ed1[b * 512 + i];
    if (tid < 32) ess[tid] = es1[b * 512 + n0 + tid];
    const short8 onesf = {0x3F80, 0x3F80, 0x3F80, 0x3F80, 0x3F80, 0x3F80, 0x3F80, 0x3F80};
    f32x4 acc[2][2], dsf[2];
#pragma unroll
    for (int a = 0; a < 2; a++) {
        dsf[a] = (f32x4){0.f, 0.f, 0.f, 0.f};
#pragma unroll
        for (int c = 0; c < 2; c++) acc[a][c] = (f32x4){0.f, 0.f, 0.f, 0.f};
    }
    for (int mc = 0; mc < 512; mc += 64) {
        __syncthreads();
        {
            const ushort_t* src = Ht + b * 65536 + mc;
            for (int u = tid; u < 1024; u += 256) {
                int c = u >> 3, ms = (u & 7) * 8;
                *(short8*)&hsb[c * 72 + ms] = *(const short8*)&src[c * 512 + ms];
            }
        }
        if (tid < 256) {                             // 256 groups: nn=g>>3, mg=g&7
            int nn = tid >> 3, mg = tid & 7;
            int ng = n0 + nn, mbase = mc + mg * 8;
            const int* grow = graph + (b * 512 + ng) * 512 + mbase;
            int4 ga = *(const int4*)grow;
            int4 gb = *(const int4*)(grow + 4);
            float es_v = ess[nn];
            int gv[8] = {ga.x, ga.y, ga.z, ga.w, gb.x, gb.y, gb.z, gb.w};
            short8 pk;
#pragma unroll
            for (int j = 0; j < 8; j++) {
                float e = es_v + eds[mbase + j];
                e = e > 0.f ? e : 0.2f * e;
                bool keep = (gv[j] > 0) | ((mbase + j) == ng);
                float w = keep ? __expf(e) : 0.f;
                pk[j] = (short)f2bf(w);
            }
            *(short8*)&ps[nn * 72 + mg * 8] = pk;
        }
        __syncthreads();
#pragma unroll
        for (int kc = 0; kc < 2; kc++) {
            short8 af[2], bfr[2];
#pragma unroll
            for (int nh = 0; nh < 2; nh++)
                af[nh] = *(const short8*)&ps[(nh * 16 + lid) * 72 + kc * 32 + quad * 8];
#pragma unroll
            for (int ch = 0; ch < 2; ch++)
                bfr[ch] = *(const short8*)&hsb[(wv * 32 + ch * 16 + lid) * 72 + kc * 32 + quad * 8];
#pragma unroll
            for (int nh = 0; nh < 2; nh++) {
#pragma unroll
                for (int ch = 0; ch < 2; ch++)
                    acc[nh][ch] = __builtin_amdgcn_mfma_f32_16x16x32_bf16(af[nh], bfr[ch], acc[nh][ch], 0, 0, 0);
                dsf[nh] = __builtin_amdgcn_mfma_f32_16x16x32_bf16(af[nh], onesf, dsf[nh], 0, 0, 0);
            }
        }
    }
#pragma unroll
    for (int nh = 0; nh < 2; nh++) {
#pragma unroll
        for (int reg = 0; reg < 4; reg++) {
            float inv = 1.0f / dsf[nh][reg];
            int row = b * 512 + n0 + nh * 16 + quad * 4 + reg;
#pragma unroll
            for (int ch = 0; ch < 2; ch++)
                O[row * 128 + wv * 32 + ch * 16 + lid] = acc[nh][ch][reg] * inv;
        }
    }
}

// ------- ln1 over concat(x[128], g1[128]) then O = y @ lin_W + lin_b ---------
__global__ __launch_bounds__(256) void ln1_linear(const float* __restrict__ x,
        const float* __restrict__ G, const float* __restrict__ g1, const float* __restrict__ b1,
        const float* __restrict__ LW, const float* __restrict__ LB,
        float* __restrict__ O) {
    __shared__ float yrow[16 * 258];
    __shared__ float lwf[8192];
    __shared__ float2 red[256];
    __shared__ float2 mvs[16];
    const int tid = threadIdx.x;
    const int row0 = blockIdx.x * 16;
    const int r = tid >> 4, t = tid & 15;
    const int row = row0 + r;
    float s = 0.f, ss = 0.f;
#pragma unroll
    for (int i4 = 0; i4 < 4; i4++) {
        int k = t * 16 + i4 * 4;
        float4 v = (k < 128) ? ((const float4*)(x + row * 128))[k >> 2]
                             : ((const float4*)(G + row * 128))[(k - 128) >> 2];
        yrow[r * 258 + k + 0] = v.x; yrow[r * 258 + k + 1] = v.y;
        yrow[r * 258 + k + 2] = v.z; yrow[r * 258 + k + 3] = v.w;
        s += v.x + v.y + v.z + v.w;
        ss += v.x * v.x + v.y * v.y + v.z * v.z + v.w * v.w;
    }
    red[tid] = make_float2(s, ss);
    __syncthreads();
    if (t == 0) {
        float S = 0.f, SS = 0.f;
        for (int i = 0; i < 16; i++) { S += red[r * 16 + i].x; SS += red[r * 16 + i].y; }
        float mu = S * (1.f / 256.f);
        float var = SS * (1.f / 256.f) - mu * mu;
        mvs[r] = make_float2(mu, rsqrtf(var + 1e-5f));
    }
    __syncthreads();
    {
        float mu = mvs[r].x, rstd = mvs[r].y;
#pragma unroll
        for (int i = 0; i < 16; i++) {
            int k = t * 16 + i;
            yrow[r * 258 + k] = (yrow[r * 258 + k] - mu) * rstd * g1[k] + b1[k];
        }
    }
    float4 acc[2];
    acc[0] = make_float4(0.f, 0.f, 0.f, 0.f);
    acc[1] = make_float4(0.f, 0.f, 0.f, 0.f);
    for (int qr = 0; qr < 4; qr++) {
        __syncthreads();
        {
            float4* l4 = (float4*)lwf;
            const float4* W4 = (const float4*)(LW + qr * 8192);
            for (int i = tid; i < 2048; i += 256) l4[i] = W4[i];
        }
        __syncthreads();
        const float4* w4 = (const float4*)lwf;
        for (int k = 0; k < 64; k++) {
            float yv = yrow[r * 258 + qr * 64 + k];
#pragma unroll
            for (int j = 0; j < 2; j++) {
                float4 wv = w4[k * 32 + t + 16 * j];
                acc[j].x = fmaf(yv, wv.x, acc[j].x);
                acc[j].y = fmaf(yv, wv.y, acc[j].y);
                acc[j].z = fmaf(yv, wv.z, acc[j].z);
                acc[j].w = fmaf(yv, wv.w, acc[j].w);
            }
        }
    }
    float4* O4 = (float4*)O;
#pragma unroll
    for (int j = 0; j < 2; j++) {
        int c = 4 * t + 64 * j;
        acc[j].x += LB[c + 0]; acc[j].y += LB[c + 1];
        acc[j].z += LB[c + 2]; acc[j].w += LB[c + 3];
        O4[row * 32 + t + 16 * j] = acc[j];
    }
}

// --- tail: enc=gelu(m@W0+b0)@W1+b1 ; ln2(m+enc) ; gelu(@oh_W+oh_b) ; ln3 -----
__global__ __launch_bounds__(256) void tail_fused(const float* __restrict__ M,
        const float* __restrict__ W0g, const float* __restrict__ B0g,
        const float* __restrict__ W1g, const float* __restrict__ B1g,
        const float* __restrict__ g2, const float* __restrict__ b2,
        const float* __restrict__ Wog, const float* __restrict__ Bog,
        const float* __restrict__ g3, const float* __restrict__ b3,
        float* __restrict__ out) {
    __shared__ float wh[8192];
    __shared__ float mrow[16 * 132];
    __shared__ float trow[16 * 132];
    __shared__ float rrow[16 * 132];
    __shared__ float2 red[256];
    __shared__ float2 mvs[16];
    const int tid = threadIdx.x;
    const int row0 = blockIdx.x * 16;
    const int r = tid >> 4, t = tid & 15;
    const int row = row0 + r;
    {
        const float4* M4 = (const float4*)(M + row0 * 128);
        for (int i = tid; i < 512; i += 256) {
            int rr_ = i >> 5, f4 = i & 31;
            ((float4*)(mrow + rr_ * 132))[f4] = M4[rr_ * 32 + f4];
        }
    }
    float4 acc[2];
#pragma unroll
    for (int j = 0; j < 2; j++) {
        int c = 4 * t + 64 * j;
        acc[j] = make_float4(B0g[c], B0g[c + 1], B0g[c + 2], B0g[c + 3]);
    }
    for (int half = 0; half < 2; half++) {
        __syncthreads();
        {
            float4* w4w = (float4*)wh;
            const float4* W4 = (const float4*)(W0g + half * 8192);
            for (int i = tid; i < 2048; i += 256) w4w[i] = W4[i];
        }
        __syncthreads();
        const float4* w4 = (const float4*)wh;
        for (int k = 0; k < 64; k++) {
            float mv = mrow[r * 132 + half * 64 + k];
#pragma unroll
            for (int j = 0; j < 2; j++) {
                float4 wv = w4[k * 32 + t + 16 * j];
                acc[j].x = fmaf(mv, wv.x, acc[j].x);
                acc[j].y = fmaf(mv, wv.y, acc[j].y);
                acc[j].z = fmaf(mv, wv.z, acc[j].z);
                acc[j].w = fmaf(mv, wv.w, acc[j].w);
            }
        }
    }
    {
        float4* t4 = (float4*)trow;
#pragma unroll
        for (int j = 0; j < 2; j++) {
            float4 v;
            v.x = gelu_f(acc[j].x); v.y = gelu_f(acc[j].y);
            v.z = gelu_f(acc[j].z); v.w = gelu_f(acc[j].w);
            t4[r * 33 + t + 16 * j] = v;
        }
    }
    float4 acc2[2];
#pragma unroll
    for (int j = 0; j < 2; j++) {
        int c = 4 * t + 64 * j;
        acc2[j] = make_float4(B1g[c], B1g[c + 1], B1g[c + 2], B1g[c + 3]);
    }
    for (int half = 0; half < 2; half++) {
        __syncthreads();
        {
            float4* w4w = (float4*)wh;
            const float4* W4 = (const float4*)(W1g + half * 8192);
            for (int i = tid; i < 2048; i += 256) w4w[i] = W4[i];
        }
        __syncthreads();
        const float4* w4 = (const float4*)wh;
        for (int k = 0; k < 64; k++) {
            float tv = trow[r * 132 + half * 64 + k];
#pragma unroll
            for (int j = 0; j < 2; j++) {
                float4 wv = w4[k * 32 + t + 16 * j];
                acc2[j].x = fmaf(tv, wv.x, acc2[j].x);
                acc2[j].y = fmaf(tv, wv.y, acc2[j].y);
                acc2[j].z = fmaf(tv, wv.z, acc2[j].z);
                acc2[j].w = fmaf(tv, wv.w, acc2[j].w);
            }
        }
    }
    float rr[8];
    {
        float s = 0.f, ss = 0.f;
#pragma unroll
        for (int j = 0; j < 2; j++) {
            int c = 4 * t + 64 * j;
            float v0 = mrow[r * 132 + c + 0] + acc2[j].x;
            float v1 = mrow[r * 132 + c + 1] + acc2[j].y;
            float v2 = mrow[r * 132 + c + 2] + acc2[j].z;
            float v3 = mrow[r * 132 + c + 3] + acc2[j].w;
            rr[j * 4 + 0] = v0; rr[j * 4 + 1] = v1; rr[j * 4 + 2] = v2; rr[j * 4 + 3] = v3;
            s += v0 + v1 + v2 + v3;
            ss += v0 * v0 + v1 * v1 + v2 * v2 + v3 * v3;
        }
        red[tid] = make_float2(s, ss);
    }
    __syncthreads();
    if (t == 0) {
        float S = 0.f, SS = 0.f;
        for (int i = 0; i < 16; i++) { S += red[r * 16 + i].x; SS += red[r * 16 + i].y; }
        float mu = S * (1.f / 128.f);
        float var = SS * (1.f / 128.f) - mu * mu;
        mvs[r] = make_float2(mu, rsqrtf(var + 1e-5f));
    }
    __syncthreads();
    {
        float mu = mvs[r].x, rstd = mvs[r].y;
        float4* r4 = (float4*)rrow;
#pragma unroll
        for (int j = 0; j < 2; j++) {
            int c = 4 * t + 64 * j;
            float4 v;
            v.x = (rr[j * 4 + 0] - mu) * rstd * g2[c + 0] + b2[c + 0];
            v.y = (rr[j * 4 + 1] - mu) * rstd * g2[c + 1] + b2[c + 1];
            v.z = (rr[j * 4 + 2] - mu) * rstd * g2[c + 2] + b2[c + 2];
            v.w = (rr[j * 4 + 3] - mu) * rstd * g2[c + 3] + b2[c + 3];
            r4[r * 33 + t + 16 * j] = v;
        }
    }
    float4 acc3[2];
#pragma unroll
    for (int j = 0; j < 2; j++) {
        int c = 4 * t + 64 * j;
        acc3[j] = make_float4(Bog[c], Bog[c + 1], Bog[c + 2], Bog[c + 3]);
    }
    for (int half = 0; half < 2; half++) {
        __syncthreads();
        {
            float4* w4w = (float4*)wh;
            const float4* W4 = (const float4*)(Wog + half * 8192);
            for (int i = tid; i < 2048; i += 256) w4w[i] = W4[i];
        }
        __syncthreads();
        const float4* w4 = (const float4*)wh;
        for (int k = 0; k < 64; k++) {
            float rv = rrow[r * 132 + half * 64 + k];
#pragma unroll
            for (int j = 0; j < 2; j++) {
                float4 wv = w4[k * 32 + t + 16 * j];
                acc3[j].x = fmaf(rv, wv.x, acc3[j].x);
                acc3[j].y = fmaf(rv, wv.y, acc3[j].y);
                acc3[j].z = fmaf(rv, wv.z, acc3[j].z);
                acc3[j].w = fmaf(rv, wv.w, acc3[j].w);
            }
        }
    }
    float vv[8];
    {
        float s = 0.f, ss = 0.f;
        float a[8] = {acc3[0].x, acc3[0].y, acc3[0].z, acc3[0].w,
                      acc3[1].x, acc3[1].y, acc3[1].z, acc3[1].w};
#pragma unroll
        for (int i = 0; i < 8; i++) {
            float g = gelu_f(a[i]);
            vv[i] = g; s += g; ss += g * g;
        }
        red[tid] = make_float2(s, ss);
    }
    __syncthreads();
    if (t == 0) {
        float S = 0.f, SS = 0.f;
        for (int i = 0; i < 16; i++) { S += red[r * 16 + i].x; SS += red[r * 16 + i].y; }
        float mu = S * (1.f / 128.f);
        float var = SS * (1.f / 128.f) - mu * mu;
        mvs[r] = make_float2(mu, rsqrtf(var + 1e-5f));
    }
    __syncthreads();
    {
        float mu = mvs[r].x, rstd = mvs[r].y;
        float4* o4 = (float4*)out;
#pragma unroll
        for (int j = 0; j < 2; j++) {
            int c = 4 * t + 64 * j;
            float4 v;
            v.x = (vv[j * 4 + 0] - mu) * rstd * g3[c + 0] + b3[c + 0];
            v.y = (vv[j * 4 + 1] - mu) * rstd * g3[c + 1] + b3[c + 1];
            v.z = (vv[j * 4 + 2] - mu) * rstd * g3[c + 2] + b3[c + 2];
            v.w = (vv[j * 4 + 3] - mu) * rstd * g3[c + 3] + b3[c + 3];
            o4[row * 32 + t + 16 * j] = v;
        }
    }
}

extern "C" void kernel_launch(void* const* d_in, const int* in_sizes, int n_in,
                              void* d_out, int out_size, void* d_ws, size_t ws_size,
                              hipStream_t stream) {
    const float* x      = (const float*)d_in[0];
    const int*   graph  = (const int*)d_in[1];
    const float* W0     = (const float*)d_in[2];
    const float* a_src0 = (const float*)d_in[3];
    const float* a_dst0 = (const float*)d_in[4];
    const float* W1     = (const float*)d_in[5];
    const float* a_src1 = (const float*)d_in[6];
    const float* a_dst1 = (const float*)d_in[7];
    const float* ln1_g  = (const float*)d_in[8];
    const float* ln1_b  = (const float*)d_in[9];
    const float* lin_W  = (const float*)d_in[10];
    const float* lin_b  = (const float*)d_in[11];
    const float* me_W0  = (const float*)d_in[12];
    const float* me_b0  = (const float*)d_in[13];
    const float* me_W1  = (const float*)d_in[14];
    const float* me_b1  = (const float*)d_in[15];
    const float* ln2_g  = (const float*)d_in[16];
    const float* ln2_b  = (const float*)d_in[17];
    const float* oh_W   = (const float*)d_in[18];
    const float* oh_b   = (const float*)d_in[19];
    const float* ln3_g  = (const float*)d_in[20];
    const float* ln3_b  = (const float*)d_in[21];
    float* out = (float*)d_out;

    float* ws  = (float*)d_ws;
    float*    fA  = ws;                          // 2097152 floats
    float*    fB  = ws + 2097152;                // 2097152 floats
    ushort_t* Ht  = (ushort_t*)(ws + 4194304);   // 2097152 bf16 = 1048576 floats
    float*    e0s = ws + 5242880;                // 65536
    float*    e0d = e0s + 65536;                 // 65536
    float*    e1s = e0d + 65536;                 // 16384
    float*    e1d = e1s + 16384;                 // 16384

    gemm128t<<<512, 256, 0, stream>>>(x, W0, fA, Ht);                          // h0 + h0t
    attn_coef0<<<256, 256, 0, stream>>>(fA, a_src0, a_dst0, e0s, e0d);
    gat0_mfma<<<dim3(16, 32), 256, 0, stream>>>(Ht, e0s, e0d, graph, fB);      // m = elu(gat0)
    gemm128t<<<512, 256, 0, stream>>>(fB, W1, fA, Ht);                         // h1 + h1t
    attn_coef1<<<64, 256, 0, stream>>>(fA, a_src1, a_dst1, e1s, e1d);
    gat1_mfma<<<dim3(16, 32), 256, 0, stream>>>(Ht, e1s, e1d, graph, fA);      // g1 -> fA
    ln1_linear<<<1024, 256, 0, stream>>>(x, fA, ln1_g, ln1_b, lin_W, lin_b, fB);
    tail_fused<<<1024, 256, 0, stream>>>(fB, me_W0, me_b0, me_W1, me_b1,
                                         ln2_g, ln2_b, oh_W, oh_b, ln3_g, ln3_b, out);
}

// Round 4
// 270.988 us; speedup vs baseline: 1.5865x; 1.1641x over previous
//
#include <hip/hip_runtime.h>
#include <cmath>

// B=32, N=512, IN=128, HID=32, HEADS=4, OUT=128. All fp32 in/out; graph int32.
// ws(floats): fA[2M] fB[2M] Ht[1M(=2M bf16)] e0s[64K] e0d[64K] e1s[16K] e1d[16K]
//   WT bf16: linT[32768] meT0[16384] meT1[16384] ohT[16384] (transposed [c][k])
// Launch: prep_wt ; gemm128t<0>(x,W0)->fA,Ht,e0 ; gat0_mfma->fB ;
//   gemm128t<1>(fB,W1)->fA,Ht,e1 ; gat1_mfma->fA ; ln1_mfma->fB ; tail_mfma->out

typedef unsigned short ushort_t;
typedef __attribute__((ext_vector_type(8))) short short8;
typedef __attribute__((ext_vector_type(4))) float f32x4;

__device__ __forceinline__ float gelu_f(float v) {
    return 0.5f * v * (1.0f + erff(v * 0.70710678118654752f));
}
__device__ __forceinline__ ushort_t f2bf(float x) {
    union { float f; unsigned u; } v; v.f = x;
    return (ushort_t)((v.u + 0x7FFFu + ((v.u >> 16) & 1u)) >> 16);
}

// ---- prep: bf16-transpose lin_W(256x128), me_W0, me_W1, oh_W (128x128) -----
__global__ __launch_bounds__(256) void prep_wt(const float* __restrict__ lin_W,
        const float* __restrict__ me_W0, const float* __restrict__ me_W1,
        const float* __restrict__ oh_W, ushort_t* __restrict__ WT) {
    int i = blockIdx.x * 256 + threadIdx.x;          // 81920 total
    if (i < 32768)      { int c = i >> 8, k = i & 255;                 WT[i] = f2bf(lin_W[k * 128 + c]); }
    else if (i < 49152) { int j = i - 32768; int c = j >> 7, k = j & 127; WT[i] = f2bf(me_W0[k * 128 + c]); }
    else if (i < 65536) { int j = i - 49152; int c = j >> 7, k = j & 127; WT[i] = f2bf(me_W1[k * 128 + c]); }
    else if (i < 81920) { int j = i - 65536; int c = j >> 7, k = j & 127; WT[i] = f2bf(oh_W[k * 128 + c]); }
}

// -- Y[R,128]=X[R,128]@W[128,128] fp32; Ht[b][c][m] bf16; fused e_src/e_dst --
// MODE 0: 4 heads of 32 (es/ed [B*4*512]); MODE 1: 1 head of 128 (es/ed [B*512])
template<int MODE>
__global__ __launch_bounds__(256) void gemm128t(const float* __restrict__ X,
        const float* __restrict__ W, float* __restrict__ Y, ushort_t* __restrict__ Ht,
        const float* __restrict__ a_s, const float* __restrict__ a_d,
        float* __restrict__ es, float* __restrict__ ed) {
    __shared__ float xs[32 * 132];
    __shared__ float wl[64 * 128];
    const int tid = threadIdx.x;
    const int row0 = blockIdx.x * 32;
    {
        const float4* X4 = (const float4*)(X + row0 * 128);
        for (int i = tid; i < 32 * 32; i += 256) {
            int r = i >> 5, f4 = i & 31;
            float4 v = X4[r * 32 + f4];
            xs[r * 132 + f4 * 4 + 0] = v.x; xs[r * 132 + f4 * 4 + 1] = v.y;
            xs[r * 132 + f4 * 4 + 2] = v.z; xs[r * 132 + f4 * 4 + 3] = v.w;
        }
    }
    const int r = tid >> 3, t = tid & 7;
    float4 acc[4];
#pragma unroll
    for (int j = 0; j < 4; j++) acc[j] = make_float4(0.f, 0.f, 0.f, 0.f);
    for (int half = 0; half < 2; half++) {
        __syncthreads();
        {
            float4* wl4 = (float4*)wl;
            const float4* W4 = (const float4*)(W + half * 8192);
            for (int i = tid; i < 2048; i += 256) wl4[i] = W4[i];
        }
        __syncthreads();
        const float4* wl4 = (const float4*)wl;
        for (int k = 0; k < 64; k++) {
            float xv = xs[r * 132 + half * 64 + k];
#pragma unroll
            for (int j = 0; j < 4; j++) {
                float4 wv = wl4[k * 32 + t + 8 * j];
                acc[j].x = fmaf(xv, wv.x, acc[j].x);
                acc[j].y = fmaf(xv, wv.y, acc[j].y);
                acc[j].z = fmaf(xv, wv.z, acc[j].z);
                acc[j].w = fmaf(xv, wv.w, acc[j].w);
            }
        }
    }
    const int row = row0 + r;
    float4* Y4 = (float4*)Y;
#pragma unroll
    for (int j = 0; j < 4; j++) Y4[row * 32 + t + 8 * j] = acc[j];
    const int b = row >> 9, m = row & 511;
    ushort_t* Hb = Ht + b * 65536 + m;
#pragma unroll
    for (int j = 0; j < 4; j++) {
        int c = 4 * t + 32 * j;
        Hb[(c + 0) * 512] = f2bf(acc[j].x);
        Hb[(c + 1) * 512] = f2bf(acc[j].y);
        Hb[(c + 2) * 512] = f2bf(acc[j].z);
        Hb[(c + 3) * 512] = f2bf(acc[j].w);
    }
    // fused attention coefficients
    float s4[4], d4[4];
#pragma unroll
    for (int j = 0; j < 4; j++) {
        int cb = 4 * t + 32 * j;
        s4[j] = acc[j].x * a_s[cb] + acc[j].y * a_s[cb + 1] + acc[j].z * a_s[cb + 2] + acc[j].w * a_s[cb + 3];
        d4[j] = acc[j].x * a_d[cb] + acc[j].y * a_d[cb + 1] + acc[j].z * a_d[cb + 2] + acc[j].w * a_d[cb + 3];
    }
    if (MODE == 0) {
#pragma unroll
        for (int st = 1; st <= 4; st <<= 1) {
#pragma unroll
            for (int j = 0; j < 4; j++) {
                s4[j] += __shfl_xor(s4[j], st);
                d4[j] += __shfl_xor(d4[j], st);
            }
        }
        if (t < 4) {
            es[(b * 4 + t) * 512 + m] = s4[t];
            ed[(b * 4 + t) * 512 + m] = d4[t];
        }
    } else {
        float s = s4[0] + s4[1] + s4[2] + s4[3];
        float d = d4[0] + d4[1] + d4[2] + d4[3];
#pragma unroll
        for (int st = 1; st <= 4; st <<= 1) { s += __shfl_xor(s, st); d += __shfl_xor(d, st); }
        if (t == 0) { es[row] = s; ed[row] = d; }
    }
}

// --------- GAT0 via MFMA (XOR-swizzled LDS granules), softmax+ELU ------------
__global__ __launch_bounds__(256) void gat0_mfma(const ushort_t* __restrict__ Ht,
        const float* __restrict__ es0, const float* __restrict__ ed0,
        const int* __restrict__ graph, float* __restrict__ O) {
    __shared__ __align__(16) ushort_t hsb[128 * 64];  // [c][m-granule^swz]
    __shared__ __align__(16) ushort_t ps[128 * 64];   // [hh*32+nn][m-granule^swz]
    __shared__ float eds[4 * 512];
    __shared__ float ess[4 * 32];
    const int tid = threadIdx.x;
    const int b = blockIdx.y, n0 = blockIdx.x * 32;
    const int lane = tid & 63, wv = tid >> 6;        // wv = head
    const int quad = lane >> 4, lid = lane & 15;
    for (int i = tid; i < 2048; i += 256) eds[i] = ed0[b * 2048 + i];
    if (tid < 128) ess[tid] = es0[b * 2048 + (tid >> 5) * 512 + n0 + (tid & 31)];
    const short8 onesf = {0x3F80, 0x3F80, 0x3F80, 0x3F80, 0x3F80, 0x3F80, 0x3F80, 0x3F80};
    f32x4 acc[2][2], dsf[2];
#pragma unroll
    for (int a = 0; a < 2; a++) {
        dsf[a] = (f32x4){0.f, 0.f, 0.f, 0.f};
#pragma unroll
        for (int c = 0; c < 2; c++) acc[a][c] = (f32x4){0.f, 0.f, 0.f, 0.f};
    }
    for (int mc = 0; mc < 512; mc += 64) {
        __syncthreads();
        {
            const ushort_t* src = Ht + b * 65536 + mc;
            for (int u = tid; u < 1024; u += 256) {
                int c = u >> 3, g = u & 7;
                *(short8*)&hsb[c * 64 + ((g ^ (c & 7)) * 8)] = *(const short8*)&src[c * 512 + g * 8];
            }
        }
        for (int g = tid; g < 1024; g += 256) {      // nn=g>>5, hh=(g>>3)&3, mg=g&7
            int nn = g >> 5, hh = (g >> 3) & 3, mg = g & 7;
            int prow = hh * 32 + nn;
            int ng = n0 + nn, mbase = mc + mg * 8;
            const int* grow = graph + (b * 512 + ng) * 512 + mbase;
            int4 ga = *(const int4*)grow;
            int4 gb = *(const int4*)(grow + 4);
            float es_v = ess[hh * 32 + nn];
            int gv[8] = {ga.x, ga.y, ga.z, ga.w, gb.x, gb.y, gb.z, gb.w};
            short8 pk;
#pragma unroll
            for (int j = 0; j < 8; j++) {
                float e = es_v + eds[hh * 512 + mbase + j];
                e = e > 0.f ? e : 0.2f * e;
                bool keep = (gv[j] > 0) | ((mbase + j) == ng);
                pk[j] = (short)f2bf(keep ? __expf(e) : 0.f);
            }
            *(short8*)&ps[prow * 64 + ((mg ^ (prow & 7)) * 8)] = pk;
        }
        __syncthreads();
#pragma unroll
        for (int kc = 0; kc < 2; kc++) {
            const int gsw = ((kc * 4 + quad) ^ (lid & 7)) * 8;
            short8 af[2], bfr[2];
#pragma unroll
            for (int nh = 0; nh < 2; nh++)
                af[nh] = *(const short8*)&ps[(wv * 32 + nh * 16 + lid) * 64 + gsw];
#pragma unroll
            for (int ch = 0; ch < 2; ch++)
                bfr[ch] = *(const short8*)&hsb[(wv * 32 + ch * 16 + lid) * 64 + gsw];
#pragma unroll
            for (int nh = 0; nh < 2; nh++) {
#pragma unroll
                for (int ch = 0; ch < 2; ch++)
                    acc[nh][ch] = __builtin_amdgcn_mfma_f32_16x16x32_bf16(af[nh], bfr[ch], acc[nh][ch], 0, 0, 0);
                dsf[nh] = __builtin_amdgcn_mfma_f32_16x16x32_bf16(af[nh], onesf, dsf[nh], 0, 0, 0);
            }
        }
    }
#pragma unroll
    for (int nh = 0; nh < 2; nh++) {
#pragma unroll
        for (int reg = 0; reg < 4; reg++) {
            float inv = 1.0f / dsf[nh][reg];
            int row = b * 512 + n0 + nh * 16 + quad * 4 + reg;
#pragma unroll
            for (int ch = 0; ch < 2; ch++) {
                float v = acc[nh][ch][reg] * inv;
                v = v > 0.f ? v : expm1f(v);
                O[row * 128 + wv * 32 + ch * 16 + lid] = v;
            }
        }
    }
}

// --------- GAT1 via MFMA (XOR-swizzled), 1 head D=128 ------------------------
__global__ __launch_bounds__(256) void gat1_mfma(const ushort_t* __restrict__ Ht,
        const float* __restrict__ es1, const float* __restrict__ ed1,
        const int* __restrict__ graph, float* __restrict__ O) {
    __shared__ __align__(16) ushort_t hsb[128 * 64];
    __shared__ __align__(16) ushort_t ps[32 * 64];
    __shared__ float eds[512];
    __shared__ float ess[32];
    const int tid = threadIdx.x;
    const int b = blockIdx.y, n0 = blockIdx.x * 32;
    const int lane = tid & 63, wv = tid >> 6;        // wv = col-block
    const int quad = lane >> 4, lid = lane & 15;
    for (int i = tid; i < 512; i += 256) eds[i] = ed1[b * 512 + i];
    if (tid < 32) ess[tid] = es1[b * 512 + n0 + tid];
    const short8 onesf = {0x3F80, 0x3F80, 0x3F80, 0x3F80, 0x3F80, 0x3F80, 0x3F80, 0x3F80};
    f32x4 acc[2][2], dsf[2];
#pragma unroll
    for (int a = 0; a < 2; a++) {
        dsf[a] = (f32x4){0.f, 0.f, 0.f, 0.f};
#pragma unroll
        for (int c = 0; c < 2; c++) acc[a][c] = (f32x4){0.f, 0.f, 0.f, 0.f};
    }
    for (int mc = 0; mc < 512; mc += 64) {
        __syncthreads();
        {
            const ushort_t* src = Ht + b * 65536 + mc;
            for (int u = tid; u < 1024; u += 256) {
                int c = u >> 3, g = u & 7;
                *(short8*)&hsb[c * 64 + ((g ^ (c & 7)) * 8)] = *(const short8*)&src[c * 512 + g * 8];
            }
        }
        if (tid < 256) {
            int nn = tid >> 3, mg = tid & 7;
            int ng = n0 + nn, mbase = mc + mg * 8;
            const int* grow = graph + (b * 512 + ng) * 512 + mbase;
            int4 ga = *(const int4*)grow;
            int4 gb = *(const int4*)(grow + 4);
            float es_v = ess[nn];
            int gv[8] = {ga.x, ga.y, ga.z, ga.w, gb.x, gb.y, gb.z, gb.w};
            short8 pk;
#pragma unroll
            for (int j = 0; j < 8; j++) {
                float e = es_v + eds[mbase + j];
                e = e > 0.f ? e : 0.2f * e;
                bool keep = (gv[j] > 0) | ((mbase + j) == ng);
                pk[j] = (short)f2bf(keep ? __expf(e) : 0.f);
            }
            *(short8*)&ps[nn * 64 + ((mg ^ (nn & 7)) * 8)] = pk;
        }
        __syncthreads();
#pragma unroll
        for (int kc = 0; kc < 2; kc++) {
            const int gsw = ((kc * 4 + quad) ^ (lid & 7)) * 8;
            short8 af[2], bfr[2];
#pragma unroll
            for (int nh = 0; nh < 2; nh++)
                af[nh] = *(const short8*)&ps[(nh * 16 + lid) * 64 + gsw];
#pragma unroll
            for (int ch = 0; ch < 2; ch++)
                bfr[ch] = *(const short8*)&hsb[(wv * 32 + ch * 16 + lid) * 64 + gsw];
#pragma unroll
            for (int nh = 0; nh < 2; nh++) {
#pragma unroll
                for (int ch = 0; ch < 2; ch++)
                    acc[nh][ch] = __builtin_amdgcn_mfma_f32_16x16x32_bf16(af[nh], bfr[ch], acc[nh][ch], 0, 0, 0);
                dsf[nh] = __builtin_amdgcn_mfma_f32_16x16x32_bf16(af[nh], onesf, dsf[nh], 0, 0, 0);
            }
        }
    }
#pragma unroll
    for (int nh = 0; nh < 2; nh++) {
#pragma unroll
        for (int reg = 0; reg < 4; reg++) {
            float inv = 1.0f / dsf[nh][reg];
            int row = b * 512 + n0 + nh * 16 + quad * 4 + reg;
#pragma unroll
            for (int ch = 0; ch < 2; ch++)
                O[row * 128 + wv * 32 + ch * 16 + lid] = acc[nh][ch][reg] * inv;
        }
    }
}

// ------ ln1(concat(x,G)) then MFMA vs linT[128][256]; block = 64 rows --------
__global__ __launch_bounds__(256) void ln1_mfma(const float* __restrict__ x,
        const float* __restrict__ G, const float* __restrict__ g1, const float* __restrict__ b1,
        const ushort_t* __restrict__ linT, const float* __restrict__ LB,
        float* __restrict__ O) {
    __shared__ __align__(16) ushort_t ybuf[64 * 256];  // 32 KB
    const int tid = threadIdx.x;
    const int row0 = blockIdx.x * 64;
    const int w = tid >> 6, lane = tid & 63;
    const int quad = lane >> 4, lid = lane & 15;
    const int rloc = w * 16 + lid;                   // LN row for this lane
    const int grow = row0 + rloc;
    const float4* xp = (const float4*)(x + grow * 128);
    const float4* gp = (const float4*)(G + grow * 128);
    float s = 0.f, ss = 0.f;
#pragma unroll
    for (int i = 0; i < 16; i++) {
        int c4 = quad * 16 + i;                      // float4 index over 256 cols
        float4 v = (c4 < 32) ? xp[c4] : gp[c4 - 32];
        s += v.x + v.y + v.z + v.w;
        ss += v.x * v.x + v.y * v.y + v.z * v.z + v.w * v.w;
    }
    s += __shfl_xor(s, 16); s += __shfl_xor(s, 32);
    ss += __shfl_xor(ss, 16); ss += __shfl_xor(ss, 32);
    float mu = s * (1.f / 256.f);
    float var = ss * (1.f / 256.f) - mu * mu;
    float rstd = rsqrtf(var + 1e-5f);
#pragma unroll
    for (int i2 = 0; i2 < 8; i2++) {
        int g = quad * 8 + i2, c0 = g * 8;
        float4 a = (c0 < 128) ? xp[c0 >> 2] : gp[(c0 - 128) >> 2];
        float4 bb = (c0 < 128) ? xp[(c0 >> 2) + 1] : gp[((c0 - 128) >> 2) + 1];
        float vv[8] = {a.x, a.y, a.z, a.w, bb.x, bb.y, bb.z, bb.w};
        short8 p;
#pragma unroll
        for (int e = 0; e < 8; e++)
            p[e] = (short)f2bf((vv[e] - mu) * rstd * g1[c0 + e] + b1[c0 + e]);
        *(short8*)&ybuf[rloc * 256 + ((g ^ (rloc & 7)) * 8)] = p;
    }
    // wave-local: this wave wrote rows w*16..w*16+15 and reads the same rows
    short8 af[8];
#pragma unroll
    for (int ks = 0; ks < 8; ks++)
        af[ks] = *(const short8*)&ybuf[rloc * 256 + (((ks * 4 + quad) ^ (rloc & 7)) * 8)];
    f32x4 C[8];
#pragma unroll
    for (int ct = 0; ct < 8; ct++) C[ct] = (f32x4){0.f, 0.f, 0.f, 0.f};
#pragma unroll
    for (int ct = 0; ct < 8; ct++) {
        const ushort_t* bp = linT + (ct * 16 + lid) * 256 + quad * 8;
#pragma unroll
        for (int ks = 0; ks < 8; ks++) {
            short8 bf = *(const short8*)&bp[ks * 32];
            C[ct] = __builtin_amdgcn_mfma_f32_16x16x32_bf16(af[ks], bf, C[ct], 0, 0, 0);
        }
    }
#pragma unroll
    for (int ct = 0; ct < 8; ct++) {
        int col = ct * 16 + lid;
        float bias = LB[col];
#pragma unroll
        for (int reg = 0; reg < 4; reg++)
            O[(row0 + w * 16 + quad * 4 + reg) * 128 + col] = C[ct][reg] + bias;
    }
}

// ----- tail via MFMA: gelu(m@meT0+b0)@meT1+b1 ; ln2(m+enc) ; gelu(@ohT+ob) ; ln3
__global__ __launch_bounds__(256) void tail_mfma(const float* __restrict__ M,
        const ushort_t* __restrict__ meT0, const float* __restrict__ B0,
        const ushort_t* __restrict__ meT1, const float* __restrict__ B1,
        const float* __restrict__ g2, const float* __restrict__ b2,
        const ushort_t* __restrict__ ohT, const float* __restrict__ ob,
        const float* __restrict__ g3, const float* __restrict__ b3,
        float* __restrict__ out) {
    __shared__ __align__(16) ushort_t abuf[64 * 128]; // bf16 m, swizzled
    __shared__ __align__(16) ushort_t tbuf[64 * 128]; // phase scratch, swizzled
    const int tid = threadIdx.x;
    const int row0 = blockIdx.x * 64;
    const int w = tid >> 6, lane = tid & 63;
    const int quad = lane >> 4, lid = lane & 15;
    for (int u = tid; u < 1024; u += 256) {
        int r = u >> 4, g = u & 15;
        const float4* src = (const float4*)(M + (row0 + r) * 128 + g * 8);
        float4 a = src[0], b = src[1];
        short8 p;
        p[0] = (short)f2bf(a.x); p[1] = (short)f2bf(a.y);
        p[2] = (short)f2bf(a.z); p[3] = (short)f2bf(a.w);
        p[4] = (short)f2bf(b.x); p[5] = (short)f2bf(b.y);
        p[6] = (short)f2bf(b.z); p[7] = (short)f2bf(b.w);
        *(short8*)&abuf[r * 128 + ((g ^ (r & 7)) * 8)] = p;
    }
    __syncthreads();
    const int arow = w * 16 + lid;
    // ---- phase 1: C = m @ me_W0 ----
    short8 af[4];
#pragma unroll
    for (int kc = 0; kc < 4; kc++)
        af[kc] = *(const short8*)&abuf[arow * 128 + (((kc * 4 + quad) ^ (lid & 7)) * 8)];
    f32x4 C[8];
#pragma unroll
    for (int ct = 0; ct < 8; ct++) C[ct] = (f32x4){0.f, 0.f, 0.f, 0.f};
#pragma unroll
    for (int ct = 0; ct < 8; ct++) {
        const ushort_t* bp = meT0 + (ct * 16 + lid) * 128 + quad * 8;
#pragma unroll
        for (int kc = 0; kc < 4; kc++) {
            short8 bf = *(const short8*)&bp[kc * 32];
            C[ct] = __builtin_amdgcn_mfma_f32_16x16x32_bf16(af[kc], bf, C[ct], 0, 0, 0);
        }
    }
#pragma unroll
    for (int ct = 0; ct < 8; ct++) {
        int col = ct * 16 + lid;
        float bias = B0[col];
        int g = col >> 3, pos = lid & 7;
#pragma unroll
        for (int reg = 0; reg < 4; reg++) {
            int r2 = quad * 4 + reg;
            float v = gelu_f(C[ct][reg] + bias);
            tbuf[(w * 16 + r2) * 128 + ((g ^ (r2 & 7)) * 8) + pos] = f2bf(v);
        }
    }
    // ---- phase 2: enc = t @ me_W1 + b1 ; rr = m + enc ; ln2 ----
#pragma unroll
    for (int kc = 0; kc < 4; kc++)
        af[kc] = *(const short8*)&tbuf[arow * 128 + (((kc * 4 + quad) ^ (lid & 7)) * 8)];
#pragma unroll
    for (int ct = 0; ct < 8; ct++) C[ct] = (f32x4){0.f, 0.f, 0.f, 0.f};
#pragma unroll
    for (int ct = 0; ct < 8; ct++) {
        const ushort_t* bp = meT1 + (ct * 16 + lid) * 128 + quad * 8;
#pragma unroll
        for (int kc = 0; kc < 4; kc++) {
            short8 bf = *(const short8*)&bp[kc * 32];
            C[ct] = __builtin_amdgcn_mfma_f32_16x16x32_bf16(af[kc], bf, C[ct], 0, 0, 0);
        }
    }
    float sr[4] = {0.f, 0.f, 0.f, 0.f}, ssr[4] = {0.f, 0.f, 0.f, 0.f};
#pragma unroll
    for (int ct = 0; ct < 8; ct++) {
        int col = ct * 16 + lid;
        float bias = B1[col];
#pragma unroll
        for (int reg = 0; reg < 4; reg++) {
            float v = C[ct][reg] + bias + M[(row0 + w * 16 + quad * 4 + reg) * 128 + col];
            C[ct][reg] = v;
            sr[reg] += v; ssr[reg] += v * v;
        }
    }
#pragma unroll
    for (int st = 1; st <= 8; st <<= 1) {
#pragma unroll
        for (int reg = 0; reg < 4; reg++) {
            sr[reg] += __shfl_xor(sr[reg], st);
            ssr[reg] += __shfl_xor(ssr[reg], st);
        }
    }
    float mu2[4], rstd2[4];
#pragma unroll
    for (int reg = 0; reg < 4; reg++) {
        mu2[reg] = sr[reg] * (1.f / 128.f);
        float var = ssr[reg] * (1.f / 128.f) - mu2[reg] * mu2[reg];
        rstd2[reg] = rsqrtf(var + 1e-5f);
    }
#pragma unroll
    for (int ct = 0; ct < 8; ct++) {
        int col = ct * 16 + lid;
        float gv = g2[col], bv = b2[col];
        int g = col >> 3, pos = lid & 7;
#pragma unroll
        for (int reg = 0; reg < 4; reg++) {
            int r2 = quad * 4 + reg;
            float v = (C[ct][reg] - mu2[reg]) * rstd2[reg] * gv + bv;
            tbuf[(w * 16 + r2) * 128 + ((g ^ (r2 & 7)) * 8) + pos] = f2bf(v);
        }
    }
    // ---- phase 3: gelu(r @ oh_W + ob) ; ln3 ; store ----
#pragma unroll
    for (int kc = 0; kc < 4; kc++)
        af[kc] = *(const short8*)&tbuf[arow * 128 + (((kc * 4 + quad) ^ (lid & 7)) * 8)];
#pragma unroll
    for (int ct = 0; ct < 8; ct++) C[ct] = (f32x4){0.f, 0.f, 0.f, 0.f};
#pragma unroll
    for (int ct = 0; ct < 8; ct++) {
        const ushort_t* bp = ohT + (ct * 16 + lid) * 128 + quad * 8;
#pragma unroll
        for (int kc = 0; kc < 4; kc++) {
            short8 bf = *(const short8*)&bp[kc * 32];
            C[ct] = __builtin_amdgcn_mfma_f32_16x16x32_bf16(af[kc], bf, C[ct], 0, 0, 0);
        }
    }
#pragma unroll
    for (int reg = 0; reg < 4; reg++) { sr[reg] = 0.f; ssr[reg] = 0.f; }
#pragma unroll
    for (int ct = 0; ct < 8; ct++) {
        int col = ct * 16 + lid;
        float bias = ob[col];
#pragma unroll
        for (int reg = 0; reg < 4; reg++) {
            float v = gelu_f(C[ct][reg] + bias);
            C[ct][reg] = v;
            sr[reg] += v; ssr[reg] += v * v;
        }
    }
#pragma unroll
    for (int st = 1; st <= 8; st <<= 1) {
#pragma unroll
        for (int reg = 0; reg < 4; reg++) {
            sr[reg] += __shfl_xor(sr[reg], st);
            ssr[reg] += __shfl_xor(ssr[reg], st);
        }
    }
#pragma unroll
    for (int reg = 0; reg < 4; reg++) {
        mu2[reg] = sr[reg] * (1.f / 128.f);
        float var = ssr[reg] * (1.f / 128.f) - mu2[reg] * mu2[reg];
        rstd2[reg] = rsqrtf(var + 1e-5f);
    }
#pragma unroll
    for (int ct = 0; ct < 8; ct++) {
        int col = ct * 16 + lid;
        float gv = g3[col], bv = b3[col];
#pragma unroll
        for (int reg = 0; reg < 4; reg++)
            out[(row0 + w * 16 + quad * 4 + reg) * 128 + col] =
                (C[ct][reg] - mu2[reg]) * rstd2[reg] * gv + bv;
    }
}

extern "C" void kernel_launch(void* const* d_in, const int* in_sizes, int n_in,
                              void* d_out, int out_size, void* d_ws, size_t ws_size,
                              hipStream_t stream) {
    const float* x      = (const float*)d_in[0];
    const int*   graph  = (const int*)d_in[1];
    const float* W0     = (const float*)d_in[2];
    const float* a_src0 = (const float*)d_in[3];
    const float* a_dst0 = (const float*)d_in[4];
    const float* W1     = (const float*)d_in[5];
    const float* a_src1 = (const float*)d_in[6];
    const float* a_dst1 = (const float*)d_in[7];
    const float* ln1_g  = (const float*)d_in[8];
    const float* ln1_b  = (const float*)d_in[9];
    const float* lin_W  = (const float*)d_in[10];
    const float* lin_b  = (const float*)d_in[11];
    const float* me_W0  = (const float*)d_in[12];
    const float* me_b0  = (const float*)d_in[13];
    const float* me_W1  = (const float*)d_in[14];
    const float* me_b1  = (const float*)d_in[15];
    const float* ln2_g  = (const float*)d_in[16];
    const float* ln2_b  = (const float*)d_in[17];
    const float* oh_W   = (const float*)d_in[18];
    const float* oh_b   = (const float*)d_in[19];
    const float* ln3_g  = (const float*)d_in[20];
    const float* ln3_b  = (const float*)d_in[21];
    float* out = (float*)d_out;

    float* ws  = (float*)d_ws;
    float*    fA   = ws;                          // 2097152 floats
    float*    fB   = ws + 2097152;                // 2097152 floats
    ushort_t* Ht   = (ushort_t*)(ws + 4194304);   // 2097152 bf16
    float*    e0s  = ws + 5242880;                // 65536
    float*    e0d  = e0s + 65536;                 // 65536
    float*    e1s  = e0d + 65536;                 // 16384
    float*    e1d  = e1s + 16384;                 // 16384
    ushort_t* WT   = (ushort_t*)(e1d + 16384);    // 81920 bf16
    ushort_t* linT = WT;                          // 32768
    ushort_t* meT0 = WT + 32768;                  // 16384
    ushort_t* meT1 = WT + 49152;                  // 16384
    ushort_t* ohT  = WT + 65536;                  // 16384

    prep_wt<<<320, 256, 0, stream>>>(lin_W, me_W0, me_W1, oh_W, WT);
    gemm128t<0><<<512, 256, 0, stream>>>(x, W0, fA, Ht, a_src0, a_dst0, e0s, e0d);
    gat0_mfma<<<dim3(16, 32), 256, 0, stream>>>(Ht, e0s, e0d, graph, fB);      // m
    gemm128t<1><<<512, 256, 0, stream>>>(fB, W1, fA, Ht, a_src1, a_dst1, e1s, e1d);
    gat1_mfma<<<dim3(16, 32), 256, 0, stream>>>(Ht, e1s, e1d, graph, fA);      // g1
    ln1_mfma<<<256, 256, 0, stream>>>(x, fA, ln1_g, ln1_b, linT, lin_b, fB);   // m2
    tail_mfma<<<256, 256, 0, stream>>>(fB, meT0, me_b0, meT1, me_b1,
                                       ln2_g, ln2_b, ohT, oh_b, ln3_g, ln3_b, out);
}

// Round 5
// 227.124 us; speedup vs baseline: 1.8929x; 1.1931x over previous
//
#include <hip/hip_runtime.h>
#include <cmath>

// B=32, N=512, IN=128, HID=32, HEADS=4, OUT=128. fp32 in/out; graph int32.
// ws: fA[2M] fB[2M] Ht[2M bf16] e0s[64K] e0d[64K] e1s[16K] e1d[16K] WT[114688 bf16]
// prep_wt ; gemm_mfma<0>(x,W0T)->Ht,e0 ; gat0_mfma->fB ; gemm_mfma<1>(fB,W1T)->Ht,e1 ;
// gat1_mfma->fA ; ln1_mfma->fB ; tail_mfma->out

typedef unsigned short ushort_t;
typedef __attribute__((ext_vector_type(8))) short short8;
typedef __attribute__((ext_vector_type(4))) float f32x4;

__device__ __forceinline__ float gelu_f(float v) {
    return 0.5f * v * (1.0f + erff(v * 0.70710678118654752f));
}
__device__ __forceinline__ ushort_t f2bf(float x) {
    union { float f; unsigned u; } v; v.f = x;
    return (ushort_t)((v.u + 0x7FFFu + ((v.u >> 16) & 1u)) >> 16);
}

// ---- prep: bf16-transpose lin_W(256x128) me_W0 me_W1 oh_W W0 W1 (128x128) ---
__global__ __launch_bounds__(256) void prep_wt(const float* __restrict__ lin_W,
        const float* __restrict__ me_W0, const float* __restrict__ me_W1,
        const float* __restrict__ oh_W, const float* __restrict__ W0,
        const float* __restrict__ W1, ushort_t* __restrict__ WT) {
    int i = blockIdx.x * 256 + threadIdx.x;          // 114688 total
    if (i < 32768)       { int c = i >> 8, k = i & 255;                   WT[i] = f2bf(lin_W[k * 128 + c]); }
    else if (i < 49152)  { int j = i - 32768;  int c = j >> 7, k = j & 127; WT[i] = f2bf(me_W0[k * 128 + c]); }
    else if (i < 65536)  { int j = i - 49152;  int c = j >> 7, k = j & 127; WT[i] = f2bf(me_W1[k * 128 + c]); }
    else if (i < 81920)  { int j = i - 65536;  int c = j >> 7, k = j & 127; WT[i] = f2bf(oh_W[k * 128 + c]); }
    else if (i < 98304)  { int j = i - 81920;  int c = j >> 7, k = j & 127; WT[i] = f2bf(W0[k * 128 + c]); }
    else if (i < 114688) { int j = i - 98304;  int c = j >> 7, k = j & 127; WT[i] = f2bf(W1[k * 128 + c]); }
}

// --- MFMA gemm: Ht[b][c][m] bf16 = (X@W)^T ; fused e_src/e_dst. No fp32 Y. ---
// MODE 0: es/ed [B*4*512] (4 heads of 32 cols); MODE 1: es/ed [B*512] (1 head).
template<int MODE>
__global__ __launch_bounds__(256) void gemm_mfma(const float* __restrict__ X,
        const ushort_t* __restrict__ WTr, ushort_t* __restrict__ Ht,
        const float* __restrict__ a_s, const float* __restrict__ a_d,
        float* __restrict__ es, float* __restrict__ ed) {
    __shared__ __align__(16) ushort_t abuf[64 * 128];  // bf16 X rows, swizzled
    __shared__ __align__(16) ushort_t tbuf[128 * 64];  // C^T staging, swizzled
    const int tid = threadIdx.x;
    const int row0 = blockIdx.x * 64;
    const int b = row0 >> 9, m0 = row0 & 511;
    const int w = tid >> 6, lane = tid & 63;
    const int quad = lane >> 4, lid = lane & 15;
    for (int u = tid; u < 1024; u += 256) {
        int r = u >> 4, g = u & 15;
        const float4* src = (const float4*)(X + (row0 + r) * 128 + g * 8);
        float4 a = src[0], bb = src[1];
        short8 p;
        p[0] = (short)f2bf(a.x);  p[1] = (short)f2bf(a.y);
        p[2] = (short)f2bf(a.z);  p[3] = (short)f2bf(a.w);
        p[4] = (short)f2bf(bb.x); p[5] = (short)f2bf(bb.y);
        p[6] = (short)f2bf(bb.z); p[7] = (short)f2bf(bb.w);
        *(short8*)&abuf[r * 128 + ((g ^ (r & 7)) * 8)] = p;
    }
    __syncthreads();
    const int arow = w * 16 + lid;
    short8 af[4];
#pragma unroll
    for (int kc = 0; kc < 4; kc++)
        af[kc] = *(const short8*)&abuf[arow * 128 + (((kc * 4 + quad) ^ (lid & 7)) * 8)];
    f32x4 C[8];
#pragma unroll
    for (int ct = 0; ct < 8; ct++) C[ct] = (f32x4){0.f, 0.f, 0.f, 0.f};
#pragma unroll
    for (int ct = 0; ct < 8; ct++) {
        const ushort_t* bp = WTr + (ct * 16 + lid) * 128 + quad * 8;
#pragma unroll
        for (int kc = 0; kc < 4; kc++) {
            short8 bf = *(const short8*)&bp[kc * 32];
            C[ct] = __builtin_amdgcn_mfma_f32_16x16x32_bf16(af[kc], bf, C[ct], 0, 0, 0);
        }
    }
    // ---- fused attention coefficients ----
    if (MODE == 0) {
        float sa[4][4], da[4][4];                    // [reg][head]
#pragma unroll
        for (int r = 0; r < 4; r++)
#pragma unroll
            for (int h = 0; h < 4; h++) { sa[r][h] = 0.f; da[r][h] = 0.f; }
#pragma unroll
        for (int ct = 0; ct < 8; ct++) {
            int col = ct * 16 + lid;
            float as_c = a_s[col], ad_c = a_d[col];
#pragma unroll
            for (int r = 0; r < 4; r++) {
                sa[r][ct >> 1] = fmaf(C[ct][r], as_c, sa[r][ct >> 1]);
                da[r][ct >> 1] = fmaf(C[ct][r], ad_c, da[r][ct >> 1]);
            }
        }
#pragma unroll
        for (int st = 1; st <= 8; st <<= 1)
#pragma unroll
            for (int r = 0; r < 4; r++)
#pragma unroll
                for (int h = 0; h < 4; h++) {
                    sa[r][h] += __shfl_xor(sa[r][h], st);
                    da[r][h] += __shfl_xor(da[r][h], st);
                }
        if (lid < 4) {
#pragma unroll
            for (int r = 0; r < 4; r++) {
                float sv = (lid == 0) ? sa[r][0] : (lid == 1) ? sa[r][1] : (lid == 2) ? sa[r][2] : sa[r][3];
                float dv = (lid == 0) ? da[r][0] : (lid == 1) ? da[r][1] : (lid == 2) ? da[r][2] : da[r][3];
                int n = m0 + w * 16 + quad * 4 + r;
                es[(b * 4 + lid) * 512 + n] = sv;
                ed[(b * 4 + lid) * 512 + n] = dv;
            }
        }
    } else {
        float sa[4], da[4];
#pragma unroll
        for (int r = 0; r < 4; r++) { sa[r] = 0.f; da[r] = 0.f; }
#pragma unroll
        for (int ct = 0; ct < 8; ct++) {
            int col = ct * 16 + lid;
            float as_c = a_s[col], ad_c = a_d[col];
#pragma unroll
            for (int r = 0; r < 4; r++) {
                sa[r] = fmaf(C[ct][r], as_c, sa[r]);
                da[r] = fmaf(C[ct][r], ad_c, da[r]);
            }
        }
#pragma unroll
        for (int st = 1; st <= 8; st <<= 1)
#pragma unroll
            for (int r = 0; r < 4; r++) {
                sa[r] += __shfl_xor(sa[r], st);
                da[r] += __shfl_xor(da[r], st);
            }
        if (lid == 0) {
#pragma unroll
            for (int r = 0; r < 4; r++) {
                int n = m0 + w * 16 + quad * 4 + r;
                es[b * 512 + n] = sa[r];
                ed[b * 512 + n] = da[r];
            }
        }
    }
    // ---- Ht: transpose via LDS, coalesced bf16 stores ----
#pragma unroll
    for (int ct = 0; ct < 8; ct++) {
        int c = ct * 16 + lid;
#pragma unroll
        for (int r = 0; r < 4; r++) {
            int m = w * 16 + quad * 4 + r;
            tbuf[c * 64 + (((m >> 3) ^ (c & 7)) * 8) + (m & 7)] = f2bf(C[ct][r]);
        }
    }
    __syncthreads();
    ushort_t* Hp = Ht + b * 65536 + m0;
    for (int u = tid; u < 1024; u += 256) {
        int c = u >> 3, g = u & 7;
        *(short8*)&Hp[c * 512 + g * 8] = *(const short8*)&tbuf[c * 64 + ((g ^ (c & 7)) * 8)];
    }
}

// --------- GAT0 via MFMA; P-comp: 1 thread per (nn,mg), all 4 heads ----------
__global__ __launch_bounds__(256) void gat0_mfma(const ushort_t* __restrict__ Ht,
        const float* __restrict__ es0, const float* __restrict__ ed0,
        const int* __restrict__ graph, float* __restrict__ O) {
    __shared__ __align__(16) ushort_t hsb[128 * 64];
    __shared__ __align__(16) ushort_t ps[128 * 64];
    __shared__ float eds[4 * 512];
    __shared__ float ess[4 * 32];
    const int tid = threadIdx.x;
    const int b = blockIdx.y, n0 = blockIdx.x * 32;
    const int lane = tid & 63, wv = tid >> 6;        // wv = head
    const int quad = lane >> 4, lid = lane & 15;
    const int pn = tid >> 3, pm = tid & 7;           // P-comp mapping
    for (int i = tid; i < 2048; i += 256) eds[i] = ed0[b * 2048 + i];
    if (tid < 128) ess[tid] = es0[b * 2048 + (tid >> 5) * 512 + n0 + (tid & 31)];
    const short8 onesf = {0x3F80, 0x3F80, 0x3F80, 0x3F80, 0x3F80, 0x3F80, 0x3F80, 0x3F80};
    f32x4 acc[2][2], dsf[2];
#pragma unroll
    for (int a = 0; a < 2; a++) {
        dsf[a] = (f32x4){0.f, 0.f, 0.f, 0.f};
#pragma unroll
        for (int c = 0; c < 2; c++) acc[a][c] = (f32x4){0.f, 0.f, 0.f, 0.f};
    }
    for (int mc = 0; mc < 512; mc += 64) {
        __syncthreads();
        {
            const ushort_t* src = Ht + b * 65536 + mc;
            for (int u = tid; u < 1024; u += 256) {
                int c = u >> 3, g = u & 7;
                *(short8*)&hsb[c * 64 + ((g ^ (c & 7)) * 8)] = *(const short8*)&src[c * 512 + g * 8];
            }
        }
        {
            int ng = n0 + pn, mbase = mc + pm * 8;
            const int* grow = graph + (b * 512 + ng) * 512 + mbase;
            int4 ga = *(const int4*)grow;
            int4 gb = *(const int4*)(grow + 4);
            int gv[8] = {ga.x, ga.y, ga.z, ga.w, gb.x, gb.y, gb.z, gb.w};
            float kmask[8];
#pragma unroll
            for (int j = 0; j < 8; j++)
                kmask[j] = ((gv[j] > 0) | ((mbase + j) == ng)) ? 1.f : 0.f;
#pragma unroll
            for (int hh = 0; hh < 4; hh++) {
                float4 e0v = *(const float4*)&eds[hh * 512 + mbase];
                float4 e1v = *(const float4*)&eds[hh * 512 + mbase + 4];
                float ev[8] = {e0v.x, e0v.y, e0v.z, e0v.w, e1v.x, e1v.y, e1v.z, e1v.w};
                float es_v = ess[hh * 32 + pn];
                short8 pk;
#pragma unroll
                for (int j = 0; j < 8; j++) {
                    float e = es_v + ev[j];
                    e = fmaxf(e, 0.2f * e);
                    pk[j] = (short)f2bf(kmask[j] * __expf(e));
                }
                int prow = hh * 32 + pn;
                *(short8*)&ps[prow * 64 + ((pm ^ (prow & 7)) * 8)] = pk;
            }
        }
        __syncthreads();
#pragma unroll
        for (int kc = 0; kc < 2; kc++) {
            const int gsw = ((kc * 4 + quad) ^ (lid & 7)) * 8;
            short8 af[2], bfr[2];
#pragma unroll
            for (int nh = 0; nh < 2; nh++)
                af[nh] = *(const short8*)&ps[(wv * 32 + nh * 16 + lid) * 64 + gsw];
#pragma unroll
            for (int ch = 0; ch < 2; ch++)
                bfr[ch] = *(const short8*)&hsb[(wv * 32 + ch * 16 + lid) * 64 + gsw];
#pragma unroll
            for (int nh = 0; nh < 2; nh++) {
#pragma unroll
                for (int ch = 0; ch < 2; ch++)
                    acc[nh][ch] = __builtin_amdgcn_mfma_f32_16x16x32_bf16(af[nh], bfr[ch], acc[nh][ch], 0, 0, 0);
                dsf[nh] = __builtin_amdgcn_mfma_f32_16x16x32_bf16(af[nh], onesf, dsf[nh], 0, 0, 0);
            }
        }
    }
#pragma unroll
    for (int nh = 0; nh < 2; nh++) {
#pragma unroll
        for (int reg = 0; reg < 4; reg++) {
            float inv = 1.0f / dsf[nh][reg];
            int row = b * 512 + n0 + nh * 16 + quad * 4 + reg;
#pragma unroll
            for (int ch = 0; ch < 2; ch++) {
                float v = acc[nh][ch][reg] * inv;
                v = v > 0.f ? v : expm1f(v);
                O[row * 128 + wv * 32 + ch * 16 + lid] = v;
            }
        }
    }
}

// --------- GAT1 via MFMA, 1 head D=128; float4 eds reads ---------------------
__global__ __launch_bounds__(256) void gat1_mfma(const ushort_t* __restrict__ Ht,
        const float* __restrict__ es1, const float* __restrict__ ed1,
        const int* __restrict__ graph, float* __restrict__ O) {
    __shared__ __align__(16) ushort_t hsb[128 * 64];
    __shared__ __align__(16) ushort_t ps[32 * 64];
    __shared__ float eds[512];
    __shared__ float ess[32];
    const int tid = threadIdx.x;
    const int b = blockIdx.y, n0 = blockIdx.x * 32;
    const int lane = tid & 63, wv = tid >> 6;
    const int quad = lane >> 4, lid = lane & 15;
    const int pn = tid >> 3, pm = tid & 7;
    for (int i = tid; i < 512; i += 256) eds[i] = ed1[b * 512 + i];
    if (tid < 32) ess[tid] = es1[b * 512 + n0 + tid];
    const short8 onesf = {0x3F80, 0x3F80, 0x3F80, 0x3F80, 0x3F80, 0x3F80, 0x3F80, 0x3F80};
    f32x4 acc[2][2], dsf[2];
#pragma unroll
    for (int a = 0; a < 2; a++) {
        dsf[a] = (f32x4){0.f, 0.f, 0.f, 0.f};
#pragma unroll
        for (int c = 0; c < 2; c++) acc[a][c] = (f32x4){0.f, 0.f, 0.f, 0.f};
    }
    for (int mc = 0; mc < 512; mc += 64) {
        __syncthreads();
        {
            const ushort_t* src = Ht + b * 65536 + mc;
            for (int u = tid; u < 1024; u += 256) {
                int c = u >> 3, g = u & 7;
                *(short8*)&hsb[c * 64 + ((g ^ (c & 7)) * 8)] = *(const short8*)&src[c * 512 + g * 8];
            }
        }
        {
            int ng = n0 + pn, mbase = mc + pm * 8;
            const int* grow = graph + (b * 512 + ng) * 512 + mbase;
            int4 ga = *(const int4*)grow;
            int4 gb = *(const int4*)(grow + 4);
            int gv[8] = {ga.x, ga.y, ga.z, ga.w, gb.x, gb.y, gb.z, gb.w};
            float4 e0v = *(const float4*)&eds[mbase & 511];
            float4 e1v = *(const float4*)&eds[(mbase & 511) + 4];
            float ev[8] = {e0v.x, e0v.y, e0v.z, e0v.w, e1v.x, e1v.y, e1v.z, e1v.w};
            float es_v = ess[pn];
            short8 pk;
#pragma unroll
            for (int j = 0; j < 8; j++) {
                float e = es_v + ev[j];
                e = fmaxf(e, 0.2f * e);
                float km = ((gv[j] > 0) | ((mbase + j) == ng)) ? 1.f : 0.f;
                pk[j] = (short)f2bf(km * __expf(e));
            }
            *(short8*)&ps[pn * 64 + ((pm ^ (pn & 7)) * 8)] = pk;
        }
        __syncthreads();
#pragma unroll
        for (int kc = 0; kc < 2; kc++) {
            const int gsw = ((kc * 4 + quad) ^ (lid & 7)) * 8;
            short8 af[2], bfr[2];
#pragma unroll
            for (int nh = 0; nh < 2; nh++)
                af[nh] = *(const short8*)&ps[(nh * 16 + lid) * 64 + gsw];
#pragma unroll
            for (int ch = 0; ch < 2; ch++)
                bfr[ch] = *(const short8*)&hsb[(wv * 32 + ch * 16 + lid) * 64 + gsw];
#pragma unroll
            for (int nh = 0; nh < 2; nh++) {
#pragma unroll
                for (int ch = 0; ch < 2; ch++)
                    acc[nh][ch] = __builtin_amdgcn_mfma_f32_16x16x32_bf16(af[nh], bfr[ch], acc[nh][ch], 0, 0, 0);
                dsf[nh] = __builtin_amdgcn_mfma_f32_16x16x32_bf16(af[nh], onesf, dsf[nh], 0, 0, 0);
            }
        }
    }
#pragma unroll
    for (int nh = 0; nh < 2; nh++) {
#pragma unroll
        for (int reg = 0; reg < 4; reg++) {
            float inv = 1.0f / dsf[nh][reg];
            int row = b * 512 + n0 + nh * 16 + quad * 4 + reg;
#pragma unroll
            for (int ch = 0; ch < 2; ch++)
                O[row * 128 + wv * 32 + ch * 16 + lid] = acc[nh][ch][reg] * inv;
        }
    }
}

// ------ ln1(concat(x,G)) then MFMA vs linT[128][256]; block = 64 rows --------
__global__ __launch_bounds__(256) void ln1_mfma(const float* __restrict__ x,
        const float* __restrict__ G, const float* __restrict__ g1, const float* __restrict__ b1,
        const ushort_t* __restrict__ linT, const float* __restrict__ LB,
        float* __restrict__ O) {
    __shared__ __align__(16) ushort_t ybuf[64 * 256];
    const int tid = threadIdx.x;
    const int row0 = blockIdx.x * 64;
    const int w = tid >> 6, lane = tid & 63;
    const int quad = lane >> 4, lid = lane & 15;
    const int rloc = w * 16 + lid;
    const int grow = row0 + rloc;
    const float4* xp = (const float4*)(x + grow * 128);
    const float4* gp = (const float4*)(G + grow * 128);
    float s = 0.f, ss = 0.f;
#pragma unroll
    for (int i = 0; i < 16; i++) {
        int c4 = quad * 16 + i;
        float4 v = (c4 < 32) ? xp[c4] : gp[c4 - 32];
        s += v.x + v.y + v.z + v.w;
        ss += v.x * v.x + v.y * v.y + v.z * v.z + v.w * v.w;
    }
    s += __shfl_xor(s, 16); s += __shfl_xor(s, 32);
    ss += __shfl_xor(ss, 16); ss += __shfl_xor(ss, 32);
    float mu = s * (1.f / 256.f);
    float var = ss * (1.f / 256.f) - mu * mu;
    float rstd = rsqrtf(var + 1e-5f);
#pragma unroll
    for (int i2 = 0; i2 < 8; i2++) {
        int g = quad * 8 + i2, c0 = g * 8;
        float4 a = (c0 < 128) ? xp[c0 >> 2] : gp[(c0 - 128) >> 2];
        float4 bb = (c0 < 128) ? xp[(c0 >> 2) + 1] : gp[((c0 - 128) >> 2) + 1];
        float vv[8] = {a.x, a.y, a.z, a.w, bb.x, bb.y, bb.z, bb.w};
        short8 p;
#pragma unroll
        for (int e = 0; e < 8; e++)
            p[e] = (short)f2bf((vv[e] - mu) * rstd * g1[c0 + e] + b1[c0 + e]);
        *(short8*)&ybuf[rloc * 256 + ((g ^ (rloc & 7)) * 8)] = p;
    }
    short8 af[8];
#pragma unroll
    for (int ks = 0; ks < 8; ks++)
        af[ks] = *(const short8*)&ybuf[rloc * 256 + (((ks * 4 + quad) ^ (rloc & 7)) * 8)];
    f32x4 C[8];
#pragma unroll
    for (int ct = 0; ct < 8; ct++) C[ct] = (f32x4){0.f, 0.f, 0.f, 0.f};
#pragma unroll
    for (int ct = 0; ct < 8; ct++) {
        const ushort_t* bp = linT + (ct * 16 + lid) * 256 + quad * 8;
#pragma unroll
        for (int ks = 0; ks < 8; ks++) {
            short8 bf = *(const short8*)&bp[ks * 32];
            C[ct] = __builtin_amdgcn_mfma_f32_16x16x32_bf16(af[ks], bf, C[ct], 0, 0, 0);
        }
    }
#pragma unroll
    for (int ct = 0; ct < 8; ct++) {
        int col = ct * 16 + lid;
        float bias = LB[col];
#pragma unroll
        for (int reg = 0; reg < 4; reg++)
            O[(row0 + w * 16 + quad * 4 + reg) * 128 + col] = C[ct][reg] + bias;
    }
}

// ----- tail via MFMA: gelu(m@meT0+b0)@meT1+b1 ; ln2(m+enc) ; gelu(@ohT+ob) ; ln3
__global__ __launch_bounds__(256) void tail_mfma(const float* __restrict__ M,
        const ushort_t* __restrict__ meT0, const float* __restrict__ B0,
        const ushort_t* __restrict__ meT1, const float* __restrict__ B1,
        const float* __restrict__ g2, const float* __restrict__ b2,
        const ushort_t* __restrict__ ohT, const float* __restrict__ ob,
        const float* __restrict__ g3, const float* __restrict__ b3,
        float* __restrict__ out) {
    __shared__ __align__(16) ushort_t abuf[64 * 128];
    __shared__ __align__(16) ushort_t tbuf[64 * 128];
    const int tid = threadIdx.x;
    const int row0 = blockIdx.x * 64;
    const int w = tid >> 6, lane = tid & 63;
    const int quad = lane >> 4, lid = lane & 15;
    for (int u = tid; u < 1024; u += 256) {
        int r = u >> 4, g = u & 15;
        const float4* src = (const float4*)(M + (row0 + r) * 128 + g * 8);
        float4 a = src[0], b = src[1];
        short8 p;
        p[0] = (short)f2bf(a.x); p[1] = (short)f2bf(a.y);
        p[2] = (short)f2bf(a.z); p[3] = (short)f2bf(a.w);
        p[4] = (short)f2bf(b.x); p[5] = (short)f2bf(b.y);
        p[6] = (short)f2bf(b.z); p[7] = (short)f2bf(b.w);
        *(short8*)&abuf[r * 128 + ((g ^ (r & 7)) * 8)] = p;
    }
    __syncthreads();
    const int arow = w * 16 + lid;
    short8 af[4];
#pragma unroll
    for (int kc = 0; kc < 4; kc++)
        af[kc] = *(const short8*)&abuf[arow * 128 + (((kc * 4 + quad) ^ (lid & 7)) * 8)];
    f32x4 C[8];
#pragma unroll
    for (int ct = 0; ct < 8; ct++) C[ct] = (f32x4){0.f, 0.f, 0.f, 0.f};
#pragma unroll
    for (int ct = 0; ct < 8; ct++) {
        const ushort_t* bp = meT0 + (ct * 16 + lid) * 128 + quad * 8;
#pragma unroll
        for (int kc = 0; kc < 4; kc++) {
            short8 bf = *(const short8*)&bp[kc * 32];
            C[ct] = __builtin_amdgcn_mfma_f32_16x16x32_bf16(af[kc], bf, C[ct], 0, 0, 0);
        }
    }
#pragma unroll
    for (int ct = 0; ct < 8; ct++) {
        int col = ct * 16 + lid;
        float bias = B0[col];
        int g = col >> 3, pos = lid & 7;
#pragma unroll
        for (int reg = 0; reg < 4; reg++) {
            int r2 = quad * 4 + reg;
            float v = gelu_f(C[ct][reg] + bias);
            tbuf[(w * 16 + r2) * 128 + ((g ^ (r2 & 7)) * 8) + pos] = f2bf(v);
        }
    }
#pragma unroll
    for (int kc = 0; kc < 4; kc++)
        af[kc] = *(const short8*)&tbuf[arow * 128 + (((kc * 4 + quad) ^ (lid & 7)) * 8)];
#pragma unroll
    for (int ct = 0; ct < 8; ct++) C[ct] = (f32x4){0.f, 0.f, 0.f, 0.f};
#pragma unroll
    for (int ct = 0; ct < 8; ct++) {
        const ushort_t* bp = meT1 + (ct * 16 + lid) * 128 + quad * 8;
#pragma unroll
        for (int kc = 0; kc < 4; kc++) {
            short8 bf = *(const short8*)&bp[kc * 32];
            C[ct] = __builtin_amdgcn_mfma_f32_16x16x32_bf16(af[kc], bf, C[ct], 0, 0, 0);
        }
    }
    float sr[4] = {0.f, 0.f, 0.f, 0.f}, ssr[4] = {0.f, 0.f, 0.f, 0.f};
#pragma unroll
    for (int ct = 0; ct < 8; ct++) {
        int col = ct * 16 + lid;
        float bias = B1[col];
#pragma unroll
        for (int reg = 0; reg < 4; reg++) {
            float v = C[ct][reg] + bias + M[(row0 + w * 16 + quad * 4 + reg) * 128 + col];
            C[ct][reg] = v;
            sr[reg] += v; ssr[reg] += v * v;
        }
    }
#pragma unroll
    for (int st = 1; st <= 8; st <<= 1)
#pragma unroll
        for (int reg = 0; reg < 4; reg++) {
            sr[reg] += __shfl_xor(sr[reg], st);
            ssr[reg] += __shfl_xor(ssr[reg], st);
        }
    float mu2[4], rstd2[4];
#pragma unroll
    for (int reg = 0; reg < 4; reg++) {
        mu2[reg] = sr[reg] * (1.f / 128.f);
        float var = ssr[reg] * (1.f / 128.f) - mu2[reg] * mu2[reg];
        rstd2[reg] = rsqrtf(var + 1e-5f);
    }
#pragma unroll
    for (int ct = 0; ct < 8; ct++) {
        int col = ct * 16 + lid;
        float gv = g2[col], bv = b2[col];
        int g = col >> 3, pos = lid & 7;
#pragma unroll
        for (int reg = 0; reg < 4; reg++) {
            int r2 = quad * 4 + reg;
            float v = (C[ct][reg] - mu2[reg]) * rstd2[reg] * gv + bv;
            tbuf[(w * 16 + r2) * 128 + ((g ^ (r2 & 7)) * 8) + pos] = f2bf(v);
        }
    }
#pragma unroll
    for (int kc = 0; kc < 4; kc++)
        af[kc] = *(const short8*)&tbuf[arow * 128 + (((kc * 4 + quad) ^ (lid & 7)) * 8)];
#pragma unroll
    for (int ct = 0; ct < 8; ct++) C[ct] = (f32x4){0.f, 0.f, 0.f, 0.f};
#pragma unroll
    for (int ct = 0; ct < 8; ct++) {
        const ushort_t* bp = ohT + (ct * 16 + lid) * 128 + quad * 8;
#pragma unroll
        for (int kc = 0; kc < 4; kc++) {
            short8 bf = *(const short8*)&bp[kc * 32];
            C[ct] = __builtin_amdgcn_mfma_f32_16x16x32_bf16(af[kc], bf, C[ct], 0, 0, 0);
        }
    }
#pragma unroll
    for (int reg = 0; reg < 4; reg++) { sr[reg] = 0.f; ssr[reg] = 0.f; }
#pragma unroll
    for (int ct = 0; ct < 8; ct++) {
        int col = ct * 16 + lid;
        float bias = ob[col];
#pragma unroll
        for (int reg = 0; reg < 4; reg++) {
            float v = gelu_f(C[ct][reg] + bias);
            C[ct][reg] = v;
            sr[reg] += v; ssr[reg] += v * v;
        }
    }
#pragma unroll
    for (int st = 1; st <= 8; st <<= 1)
#pragma unroll
        for (int reg = 0; reg < 4; reg++) {
            sr[reg] += __shfl_xor(sr[reg], st);
            ssr[reg] += __shfl_xor(ssr[reg], st);
        }
#pragma unroll
    for (int reg = 0; reg < 4; reg++) {
        mu2[reg] = sr[reg] * (1.f / 128.f);
        float var = ssr[reg] * (1.f / 128.f) - mu2[reg] * mu2[reg];
        rstd2[reg] = rsqrtf(var + 1e-5f);
    }
#pragma unroll
    for (int ct = 0; ct < 8; ct++) {
        int col = ct * 16 + lid;
        float gv = g3[col], bv = b3[col];
#pragma unroll
        for (int reg = 0; reg < 4; reg++)
            out[(row0 + w * 16 + quad * 4 + reg) * 128 + col] =
                (C[ct][reg] - mu2[reg]) * rstd2[reg] * gv + bv;
    }
}

extern "C" void kernel_launch(void* const* d_in, const int* in_sizes, int n_in,
                              void* d_out, int out_size, void* d_ws, size_t ws_size,
                              hipStream_t stream) {
    const float* x      = (const float*)d_in[0];
    const int*   graph  = (const int*)d_in[1];
    const float* W0     = (const float*)d_in[2];
    const float* a_src0 = (const float*)d_in[3];
    const float* a_dst0 = (const float*)d_in[4];
    const float* W1     = (const float*)d_in[5];
    const float* a_src1 = (const float*)d_in[6];
    const float* a_dst1 = (const float*)d_in[7];
    const float* ln1_g  = (const float*)d_in[8];
    const float* ln1_b  = (const float*)d_in[9];
    const float* lin_W  = (const float*)d_in[10];
    const float* lin_b  = (const float*)d_in[11];
    const float* me_W0  = (const float*)d_in[12];
    const float* me_b0  = (const float*)d_in[13];
    const float* me_W1  = (const float*)d_in[14];
    const float* me_b1  = (const float*)d_in[15];
    const float* ln2_g  = (const float*)d_in[16];
    const float* ln2_b  = (const float*)d_in[17];
    const float* oh_W   = (const float*)d_in[18];
    const float* oh_b   = (const float*)d_in[19];
    const float* ln3_g  = (const float*)d_in[20];
    const float* ln3_b  = (const float*)d_in[21];
    float* out = (float*)d_out;

    float* ws  = (float*)d_ws;
    float*    fA   = ws;                          // 2097152 floats
    float*    fB   = ws + 2097152;                // 2097152 floats
    ushort_t* Ht   = (ushort_t*)(ws + 4194304);   // 2097152 bf16
    float*    e0s  = ws + 5242880;                // 65536
    float*    e0d  = e0s + 65536;                 // 65536
    float*    e1s  = e0d + 65536;                 // 16384
    float*    e1d  = e1s + 16384;                 // 16384
    ushort_t* WT   = (ushort_t*)(e1d + 16384);    // 114688 bf16
    ushort_t* linT = WT;                          // 32768
    ushort_t* meT0 = WT + 32768;                  // 16384
    ushort_t* meT1 = WT + 49152;                  // 16384
    ushort_t* ohT  = WT + 65536;                  // 16384
    ushort_t* W0T  = WT + 81920;                  // 16384
    ushort_t* W1T  = WT + 98304;                  // 16384

    prep_wt<<<448, 256, 0, stream>>>(lin_W, me_W0, me_W1, oh_W, W0, W1, WT);
    gemm_mfma<0><<<256, 256, 0, stream>>>(x, W0T, Ht, a_src0, a_dst0, e0s, e0d);
    gat0_mfma<<<dim3(16, 32), 256, 0, stream>>>(Ht, e0s, e0d, graph, fB);      // m
    gemm_mfma<1><<<256, 256, 0, stream>>>(fB, W1T, Ht, a_src1, a_dst1, e1s, e1d);
    gat1_mfma<<<dim3(16, 32), 256, 0, stream>>>(Ht, e1s, e1d, graph, fA);      // g1
    ln1_mfma<<<256, 256, 0, stream>>>(x, fA, ln1_g, ln1_b, linT, lin_b, fB);   // m2
    tail_mfma<<<256, 256, 0, stream>>>(fB, meT0, me_b0, meT1, me_b1,
                                       ln2_g, ln2_b, ohT, oh_b, ln3_g, ln3_b, out);
}

// Round 6
// 205.390 us; speedup vs baseline: 2.0932x; 1.1058x over previous
//
#include <hip/hip_runtime.h>
#include <cmath>

// B=32, N=512, IN=128, HID=32, HEADS=4, OUT=128. fp32 in/out; graph int32.
// 16-row blocks everywhere (1024 blocks, 4/CU): waves split output col-tiles.
// prep_wt ; gemm_mfma<0>(x,W0T)->Ht,e0 ; gat0_mfma->fB ; gemm_mfma<1>(fB,W1T)->Ht,e1 ;
// gat1_mfma->fA ; head_fused(x,fA)->out   [ln1+linear+MLP+ln2+head+ln3 fused]

typedef unsigned short ushort_t;
typedef __attribute__((ext_vector_type(8))) short short8;
typedef __attribute__((ext_vector_type(4))) float f32x4;

__device__ __forceinline__ float gelu_f(float v) {
    return 0.5f * v * (1.0f + erff(v * 0.70710678118654752f));
}
__device__ __forceinline__ ushort_t f2bf(float x) {      // round-to-nearest-even
    union { float f; unsigned u; } v; v.f = x;
    return (ushort_t)((v.u + 0x7FFFu + ((v.u >> 16) & 1u)) >> 16);
}
__device__ __forceinline__ ushort_t f2bf_t(float x) {    // truncate (hot softmax path)
    union { float f; unsigned u; } v; v.f = x;
    return (ushort_t)(v.u >> 16);
}

// ---- prep: bf16-transpose lin_W(256x128) me_W0 me_W1 oh_W W0 W1 (128x128) ---
__global__ __launch_bounds__(256) void prep_wt(const float* __restrict__ lin_W,
        const float* __restrict__ me_W0, const float* __restrict__ me_W1,
        const float* __restrict__ oh_W, const float* __restrict__ W0,
        const float* __restrict__ W1, ushort_t* __restrict__ WT) {
    int i = blockIdx.x * 256 + threadIdx.x;          // 114688 total
    if (i < 32768)       { int c = i >> 8, k = i & 255;                   WT[i] = f2bf(lin_W[k * 128 + c]); }
    else if (i < 49152)  { int j = i - 32768;  int c = j >> 7, k = j & 127; WT[i] = f2bf(me_W0[k * 128 + c]); }
    else if (i < 65536)  { int j = i - 49152;  int c = j >> 7, k = j & 127; WT[i] = f2bf(me_W1[k * 128 + c]); }
    else if (i < 81920)  { int j = i - 65536;  int c = j >> 7, k = j & 127; WT[i] = f2bf(oh_W[k * 128 + c]); }
    else if (i < 98304)  { int j = i - 81920;  int c = j >> 7, k = j & 127; WT[i] = f2bf(W0[k * 128 + c]); }
    else if (i < 114688) { int j = i - 98304;  int c = j >> 7, k = j & 127; WT[i] = f2bf(W1[k * 128 + c]); }
}

// -- 16-row MFMA gemm: Ht[b][c][m] bf16 = (X@W)^T ; fused e_src/e_dst. -------
// Waves split cols: wave w owns ct {w, w+4}. MODE 0: 4 heads; MODE 1: 1 head.
template<int MODE>
__global__ __launch_bounds__(256) void gemm_mfma(const float* __restrict__ X,
        const ushort_t* __restrict__ WTr, ushort_t* __restrict__ Ht,
        const float* __restrict__ a_s, const float* __restrict__ a_d,
        float* __restrict__ es, float* __restrict__ ed) {
    __shared__ __align__(16) ushort_t abuf[16 * 128];  // 4KB bf16 X, swizzled
    __shared__ __align__(16) ushort_t tb[128 * 24];    // 6KB C^T staging (stride 24)
    __shared__ float2 ered[8 * 16];                    // [ct][row] (s,d) partials
    const int tid = threadIdx.x;
    const int row0 = blockIdx.x * 16;
    const int b = row0 >> 9, m0 = row0 & 511;
    const int w = tid >> 6, lane = tid & 63;
    const int quad = lane >> 4, lid = lane & 15;
    {   // stage 16 rows bf16
        int r = tid >> 4, g = tid & 15;
        const float4* src = (const float4*)(X + (row0 + r) * 128 + g * 8);
        float4 a = src[0], bb = src[1];
        short8 p;
        p[0] = (short)f2bf(a.x);  p[1] = (short)f2bf(a.y);
        p[2] = (short)f2bf(a.z);  p[3] = (short)f2bf(a.w);
        p[4] = (short)f2bf(bb.x); p[5] = (short)f2bf(bb.y);
        p[6] = (short)f2bf(bb.z); p[7] = (short)f2bf(bb.w);
        *(short8*)&abuf[r * 128 + ((g ^ (r & 7)) * 8)] = p;
    }
    __syncthreads();
    short8 af[4];
#pragma unroll
    for (int kc = 0; kc < 4; kc++)
        af[kc] = *(const short8*)&abuf[lid * 128 + (((kc * 4 + quad) ^ (lid & 7)) * 8)];
    f32x4 C[2];
#pragma unroll
    for (int i = 0; i < 2; i++) {
        int ct = w + 4 * i;
        const ushort_t* bp = WTr + (ct * 16 + lid) * 128 + quad * 8;
        C[i] = (f32x4){0.f, 0.f, 0.f, 0.f};
#pragma unroll
        for (int kc = 0; kc < 4; kc++) {
            short8 bf = *(const short8*)&bp[kc * 32];
            C[i] = __builtin_amdgcn_mfma_f32_16x16x32_bf16(af[kc], bf, C[i], 0, 0, 0);
        }
    }
    // e partials per ct, reduced over lid
#pragma unroll
    for (int i = 0; i < 2; i++) {
        int ct = w + 4 * i, col = ct * 16 + lid;
        float as_c = a_s[col], ad_c = a_d[col];
        float s0[4], d0[4];
#pragma unroll
        for (int r = 0; r < 4; r++) { s0[r] = C[i][r] * as_c; d0[r] = C[i][r] * ad_c; }
#pragma unroll
        for (int st = 1; st <= 8; st <<= 1)
#pragma unroll
            for (int r = 0; r < 4; r++) {
                s0[r] += __shfl_xor(s0[r], st);
                d0[r] += __shfl_xor(d0[r], st);
            }
        if (lid == 0) {
#pragma unroll
            for (int r = 0; r < 4; r++)
                ered[ct * 16 + quad * 4 + r] = make_float2(s0[r], d0[r]);
        }
    }
    // C^T into tb
#pragma unroll
    for (int i = 0; i < 2; i++) {
        int c = (w + 4 * i) * 16 + lid;
#pragma unroll
        for (int r = 0; r < 4; r++)
            tb[c * 24 + quad * 4 + r] = f2bf(C[i][r]);
    }
    __syncthreads();
    if (MODE == 0) {
        if (tid < 64) {
            int row = tid & 15, h = tid >> 4;
            float2 pa = ered[(2 * h) * 16 + row], pb = ered[(2 * h + 1) * 16 + row];
            es[(b * 4 + h) * 512 + m0 + row] = pa.x + pb.x;
            ed[(b * 4 + h) * 512 + m0 + row] = pa.y + pb.y;
        }
    } else {
        if (tid < 16) {
            float S = 0.f, D = 0.f;
#pragma unroll
            for (int ct = 0; ct < 8; ct++) { float2 p = ered[ct * 16 + tid]; S += p.x; D += p.y; }
            es[b * 512 + m0 + tid] = S;
            ed[b * 512 + m0 + tid] = D;
        }
    }
    {   // coalesced Ht store: 128 c x 16 m
        int c = tid >> 1, half = tid & 1;
        *(short8*)&Ht[b * 65536 + c * 512 + m0 + half * 8] = *(const short8*)&tb[c * 24 + half * 8];
    }
}

// --------- GAT0 via MFMA, 16-row tiles; wave = head -------------------------
__global__ __launch_bounds__(256) void gat0_mfma(const ushort_t* __restrict__ Ht,
        const float* __restrict__ es0, const float* __restrict__ ed0,
        const int* __restrict__ graph, float* __restrict__ O) {
    __shared__ __align__(16) ushort_t hsb[128 * 64];   // 16KB
    __shared__ __align__(16) ushort_t ps[64 * 64];     // 8KB rows = hh*16+nn
    __shared__ float eds[2048];                        // 8KB
    __shared__ float ess[64];                          // [hh][nn]
    const int tid = threadIdx.x;
    const int b = blockIdx.y, n0 = blockIdx.x * 16;
    const int lane = tid & 63, wv = tid >> 6;          // wv = head
    const int quad = lane >> 4, lid = lane & 15;
    const int pn = tid >> 4, pg = (tid >> 1) & 7, ph = tid & 1;
    for (int i = tid; i < 2048; i += 256) eds[i] = ed0[b * 2048 + i];
    if (tid < 64) ess[tid] = es0[b * 2048 + (tid >> 4) * 512 + n0 + (tid & 15)];
    const short8 onesf = {0x3F80, 0x3F80, 0x3F80, 0x3F80, 0x3F80, 0x3F80, 0x3F80, 0x3F80};
    f32x4 acc[2], dsf;
    acc[0] = (f32x4){0.f, 0.f, 0.f, 0.f};
    acc[1] = (f32x4){0.f, 0.f, 0.f, 0.f};
    dsf = (f32x4){0.f, 0.f, 0.f, 0.f};
    for (int mc = 0; mc < 512; mc += 64) {
        __syncthreads();
        {
            const ushort_t* src = Ht + b * 65536 + mc;
            for (int u = tid; u < 1024; u += 256) {
                int c = u >> 3, g = u & 7;
                *(short8*)&hsb[c * 64 + ((g ^ (c & 7)) * 8)] = *(const short8*)&src[c * 512 + g * 8];
            }
        }
        {
            int ng = n0 + pn, mbase = mc + pg * 8;
            const int* grow = graph + (b * 512 + ng) * 512 + mbase;
            int4 ga = *(const int4*)grow;
            int4 gb = *(const int4*)(grow + 4);
            int gv[8] = {ga.x, ga.y, ga.z, ga.w, gb.x, gb.y, gb.z, gb.w};
            bool keep[8];
#pragma unroll
            for (int j = 0; j < 8; j++)
                keep[j] = (gv[j] > 0) | ((mbase + j) == ng);
#pragma unroll
            for (int hi = 0; hi < 2; hi++) {
                int hh = ph * 2 + hi;
                float es_v = ess[hh * 16 + pn];
                float4 e0v = *(const float4*)&eds[hh * 512 + mbase];
                float4 e1v = *(const float4*)&eds[hh * 512 + mbase + 4];
                float ev[8] = {e0v.x, e0v.y, e0v.z, e0v.w, e1v.x, e1v.y, e1v.z, e1v.w};
                short8 pk;
#pragma unroll
                for (int j = 0; j < 8; j++) {
                    float e = es_v + ev[j];
                    e = fmaxf(e, 0.2f * e);
                    e = keep[j] ? e : -1e30f;
                    pk[j] = (short)f2bf_t(__expf(e));
                }
                int prow = hh * 16 + pn;
                *(short8*)&ps[prow * 64 + ((pg ^ (prow & 7)) * 8)] = pk;
            }
        }
        __syncthreads();
#pragma unroll
        for (int kc = 0; kc < 2; kc++) {
            const int gsw = ((kc * 4 + quad) ^ (lid & 7)) * 8;
            short8 a = *(const short8*)&ps[(wv * 16 + lid) * 64 + gsw];
            short8 b0f = *(const short8*)&hsb[(wv * 32 + lid) * 64 + gsw];
            short8 b1f = *(const short8*)&hsb[(wv * 32 + 16 + lid) * 64 + gsw];
            acc[0] = __builtin_amdgcn_mfma_f32_16x16x32_bf16(a, b0f, acc[0], 0, 0, 0);
            acc[1] = __builtin_amdgcn_mfma_f32_16x16x32_bf16(a, b1f, acc[1], 0, 0, 0);
            dsf = __builtin_amdgcn_mfma_f32_16x16x32_bf16(a, onesf, dsf, 0, 0, 0);
        }
    }
#pragma unroll
    for (int reg = 0; reg < 4; reg++) {
        float inv = 1.0f / dsf[reg];
        int row = b * 512 + n0 + quad * 4 + reg;
#pragma unroll
        for (int ch = 0; ch < 2; ch++) {
            float v = acc[ch][reg] * inv;
            v = v > 0.f ? v : expm1f(v);             // ELU
            O[row * 128 + wv * 32 + ch * 16 + lid] = v;
        }
    }
}

// --------- GAT1 via MFMA, 16-row tiles; wave = col-block --------------------
__global__ __launch_bounds__(256) void gat1_mfma(const ushort_t* __restrict__ Ht,
        const float* __restrict__ es1, const float* __restrict__ ed1,
        const int* __restrict__ graph, float* __restrict__ O) {
    __shared__ __align__(16) ushort_t hsb[128 * 64];
    __shared__ __align__(16) ushort_t ps[16 * 64];
    __shared__ float eds[512];
    __shared__ float ess[16];
    const int tid = threadIdx.x;
    const int b = blockIdx.y, n0 = blockIdx.x * 16;
    const int lane = tid & 63, wv = tid >> 6;
    const int quad = lane >> 4, lid = lane & 15;
    for (int i = tid; i < 512; i += 256) eds[i] = ed1[b * 512 + i];
    if (tid < 16) ess[tid] = es1[b * 512 + n0 + tid];
    const short8 onesf = {0x3F80, 0x3F80, 0x3F80, 0x3F80, 0x3F80, 0x3F80, 0x3F80, 0x3F80};
    f32x4 acc[2], dsf;
    acc[0] = (f32x4){0.f, 0.f, 0.f, 0.f};
    acc[1] = (f32x4){0.f, 0.f, 0.f, 0.f};
    dsf = (f32x4){0.f, 0.f, 0.f, 0.f};
    for (int mc = 0; mc < 512; mc += 64) {
        __syncthreads();
        {
            const ushort_t* src = Ht + b * 65536 + mc;
            for (int u = tid; u < 1024; u += 256) {
                int c = u >> 3, g = u & 7;
                *(short8*)&hsb[c * 64 + ((g ^ (c & 7)) * 8)] = *(const short8*)&src[c * 512 + g * 8];
            }
        }
        if (tid < 128) {
            int pn = tid >> 3, pg = tid & 7;
            int ng = n0 + pn, mbase = mc + pg * 8;
            const int* grow = graph + (b * 512 + ng) * 512 + mbase;
            int4 ga = *(const int4*)grow;
            int4 gb = *(const int4*)(grow + 4);
            int gv[8] = {ga.x, ga.y, ga.z, ga.w, gb.x, gb.y, gb.z, gb.w};
            float4 e0v = *(const float4*)&eds[mbase & 511];
            float4 e1v = *(const float4*)&eds[(mbase & 511) + 4];
            float ev[8] = {e0v.x, e0v.y, e0v.z, e0v.w, e1v.x, e1v.y, e1v.z, e1v.w};
            float es_v = ess[pn];
            short8 pk;
#pragma unroll
            for (int j = 0; j < 8; j++) {
                float e = es_v + ev[j];
                e = fmaxf(e, 0.2f * e);
                e = ((gv[j] > 0) | ((mbase + j) == ng)) ? e : -1e30f;
                pk[j] = (short)f2bf_t(__expf(e));
            }
            *(short8*)&ps[pn * 64 + ((pg ^ (pn & 7)) * 8)] = pk;
        }
        __syncthreads();
#pragma unroll
        for (int kc = 0; kc < 2; kc++) {
            const int gsw = ((kc * 4 + quad) ^ (lid & 7)) * 8;
            short8 a = *(const short8*)&ps[lid * 64 + gsw];
            short8 b0f = *(const short8*)&hsb[(wv * 32 + lid) * 64 + gsw];
            short8 b1f = *(const short8*)&hsb[(wv * 32 + 16 + lid) * 64 + gsw];
            acc[0] = __builtin_amdgcn_mfma_f32_16x16x32_bf16(a, b0f, acc[0], 0, 0, 0);
            acc[1] = __builtin_amdgcn_mfma_f32_16x16x32_bf16(a, b1f, acc[1], 0, 0, 0);
            dsf = __builtin_amdgcn_mfma_f32_16x16x32_bf16(a, onesf, dsf, 0, 0, 0);
        }
    }
#pragma unroll
    for (int reg = 0; reg < 4; reg++) {
        float inv = 1.0f / dsf[reg];
        int row = b * 512 + n0 + quad * 4 + reg;
#pragma unroll
        for (int ch = 0; ch < 2; ch++)
            O[row * 128 + wv * 32 + ch * 16 + lid] = acc[ch][reg] * inv;
    }
}

// ---- head_fused: ln1(x||G)@lin_W+b ; MLP(gelu)+res ; ln2 ; gelu(oh) ; ln3 ---
// 16 rows/block, 1024 blocks; wave w owns ct {w, w+4} for every GEMM.
__global__ __launch_bounds__(256) void head_fused(const float* __restrict__ x,
        const float* __restrict__ G, const float* __restrict__ g1, const float* __restrict__ b1,
        const ushort_t* __restrict__ linT, const float* __restrict__ LB,
        const ushort_t* __restrict__ meT0, const float* __restrict__ B0,
        const ushort_t* __restrict__ meT1, const float* __restrict__ B1,
        const float* __restrict__ g2, const float* __restrict__ b2,
        const ushort_t* __restrict__ ohT, const float* __restrict__ ob,
        const float* __restrict__ g3, const float* __restrict__ b3,
        float* __restrict__ out) {
    __shared__ __align__(16) ushort_t ybuf[16 * 256];  // 8KB ln1 output bf16
    __shared__ __align__(16) ushort_t abuf[16 * 128];  // 4KB m2 bf16
    __shared__ __align__(16) ushort_t tbuf[16 * 128];  // 4KB phase scratch
    __shared__ float2 red[4 * 16];                     // [wave][row] partials
    __shared__ float2 mvs[16];
    const int tid = threadIdx.x;
    const int row0 = blockIdx.x * 16;
    const int w = tid >> 6, lane = tid & 63;
    const int quad = lane >> 4, lid = lane & 15;
    // ---- LN1 stats + ybuf ----
    const int r = tid >> 4, c16 = tid & 15;
    const float4* xp = (const float4*)(x + (row0 + r) * 128);
    const float4* gp = (const float4*)(G + (row0 + r) * 128);
    float4 vv4[4];
    float s = 0.f, ss = 0.f;
#pragma unroll
    for (int i = 0; i < 4; i++) {
        int c4 = c16 * 4 + i;
        float4 v = (c4 < 32) ? xp[c4] : gp[c4 - 32];
        vv4[i] = v;
        s += v.x + v.y + v.z + v.w;
        ss += v.x * v.x + v.y * v.y + v.z * v.z + v.w * v.w;
    }
#pragma unroll
    for (int st = 1; st <= 8; st <<= 1) { s += __shfl_xor(s, st); ss += __shfl_xor(ss, st); }
    if (c16 == 0) {
        float mu = s * (1.f / 256.f);
        float var = ss * (1.f / 256.f) - mu * mu;
        mvs[r] = make_float2(mu, rsqrtf(var + 1e-5f));
    }
    __syncthreads();
    {
        float mu = mvs[r].x, rstd = mvs[r].y;
#pragma unroll
        for (int half = 0; half < 2; half++) {
            int g = c16 * 2 + half, c0 = g * 8;
            float va[8] = {vv4[half * 2].x, vv4[half * 2].y, vv4[half * 2].z, vv4[half * 2].w,
                           vv4[half * 2 + 1].x, vv4[half * 2 + 1].y, vv4[half * 2 + 1].z, vv4[half * 2 + 1].w};
            short8 p;
#pragma unroll
            for (int e = 0; e < 8; e++)
                p[e] = (short)f2bf((va[e] - mu) * rstd * g1[c0 + e] + b1[c0 + e]);
            *(short8*)&ybuf[r * 256 + ((g ^ (r & 7)) * 8)] = p;
        }
    }
    __syncthreads();
    // ---- GEMM1: M2 = y @ lin_W + lin_b ----
    short8 af8[8];
#pragma unroll
    for (int ks = 0; ks < 8; ks++)
        af8[ks] = *(const short8*)&ybuf[lid * 256 + (((ks * 4 + quad) ^ (lid & 7)) * 8)];
    f32x4 M2[2];
#pragma unroll
    for (int i = 0; i < 2; i++) {
        int ct = w + 4 * i;
        const ushort_t* bp = linT + (ct * 16 + lid) * 256 + quad * 8;
        M2[i] = (f32x4){0.f, 0.f, 0.f, 0.f};
#pragma unroll
        for (int ks = 0; ks < 8; ks++) {
            short8 bf = *(const short8*)&bp[ks * 32];
            M2[i] = __builtin_amdgcn_mfma_f32_16x16x32_bf16(af8[ks], bf, M2[i], 0, 0, 0);
        }
        float bias = LB[ct * 16 + lid];
#pragma unroll
        for (int reg = 0; reg < 4; reg++) M2[i][reg] += bias;
        int col = ct * 16 + lid, g = col >> 3, pos = col & 7;
#pragma unroll
        for (int reg = 0; reg < 4; reg++) {
            int rw = quad * 4 + reg;
            abuf[rw * 128 + ((g ^ (rw & 7)) * 8) + pos] = f2bf(M2[i][reg]);
        }
    }
    __syncthreads();
    // ---- phase 2: T = gelu(m2 @ me_W0 + b0) ----
    short8 at[4];
#pragma unroll
    for (int kc = 0; kc < 4; kc++)
        at[kc] = *(const short8*)&abuf[lid * 128 + (((kc * 4 + quad) ^ (lid & 7)) * 8)];
#pragma unroll
    for (int i = 0; i < 2; i++) {
        int ct = w + 4 * i;
        const ushort_t* bp = meT0 + (ct * 16 + lid) * 128 + quad * 8;
        f32x4 C = (f32x4){0.f, 0.f, 0.f, 0.f};
#pragma unroll
        for (int kc = 0; kc < 4; kc++) {
            short8 bf = *(const short8*)&bp[kc * 32];
            C = __builtin_amdgcn_mfma_f32_16x16x32_bf16(at[kc], bf, C, 0, 0, 0);
        }
        int col = ct * 16 + lid, g = col >> 3, pos = col & 7;
        float bias = B0[col];
#pragma unroll
        for (int reg = 0; reg < 4; reg++) {
            int rw = quad * 4 + reg;
            tbuf[rw * 128 + ((g ^ (rw & 7)) * 8) + pos] = f2bf(gelu_f(C[reg] + bias));
        }
    }
    __syncthreads();
    // ---- phase 3: enc = T @ me_W1 + b1 ; R = m2 + enc ; ln2 ----
#pragma unroll
    for (int kc = 0; kc < 4; kc++)
        at[kc] = *(const short8*)&tbuf[lid * 128 + (((kc * 4 + quad) ^ (lid & 7)) * 8)];
    f32x4 R[2];
    float sr[4] = {0.f, 0.f, 0.f, 0.f}, ssr[4] = {0.f, 0.f, 0.f, 0.f};
#pragma unroll
    for (int i = 0; i < 2; i++) {
        int ct = w + 4 * i;
        const ushort_t* bp = meT1 + (ct * 16 + lid) * 128 + quad * 8;
        f32x4 C = (f32x4){0.f, 0.f, 0.f, 0.f};
#pragma unroll
        for (int kc = 0; kc < 4; kc++) {
            short8 bf = *(const short8*)&bp[kc * 32];
            C = __builtin_amdgcn_mfma_f32_16x16x32_bf16(at[kc], bf, C, 0, 0, 0);
        }
        float bias = B1[ct * 16 + lid];
#pragma unroll
        for (int reg = 0; reg < 4; reg++) {
            float v = M2[i][reg] + C[reg] + bias;
            R[i][reg] = v;
            sr[reg] += v; ssr[reg] += v * v;
        }
    }
#pragma unroll
    for (int st = 1; st <= 8; st <<= 1)
#pragma unroll
        for (int reg = 0; reg < 4; reg++) {
            sr[reg] += __shfl_xor(sr[reg], st);
            ssr[reg] += __shfl_xor(ssr[reg], st);
        }
    if (lid == 0) {
#pragma unroll
        for (int reg = 0; reg < 4; reg++)
            red[w * 16 + quad * 4 + reg] = make_float2(sr[reg], ssr[reg]);
    }
    __syncthreads();
    float mu2[4], rstd2[4];
#pragma unroll
    for (int reg = 0; reg < 4; reg++) {
        float S = 0.f, SS = 0.f;
#pragma unroll
        for (int w4 = 0; w4 < 4; w4++) {
            float2 p = red[w4 * 16 + quad * 4 + reg];
            S += p.x; SS += p.y;
        }
        mu2[reg] = S * (1.f / 128.f);
        float var = SS * (1.f / 128.f) - mu2[reg] * mu2[reg];
        rstd2[reg] = rsqrtf(var + 1e-5f);
    }
#pragma unroll
    for (int i = 0; i < 2; i++) {
        int col = (w + 4 * i) * 16 + lid, g = col >> 3, pos = col & 7;
        float gv = g2[col], bv = b2[col];
#pragma unroll
        for (int reg = 0; reg < 4; reg++) {
            int rw = quad * 4 + reg;
            float v = (R[i][reg] - mu2[reg]) * rstd2[reg] * gv + bv;
            tbuf[rw * 128 + ((g ^ (rw & 7)) * 8) + pos] = f2bf(v);
        }
    }
    __syncthreads();
    // ---- phase 4: V = gelu(r @ oh_W + ob) ; ln3 ; store ----
#pragma unroll
    for (int kc = 0; kc < 4; kc++)
        at[kc] = *(const short8*)&tbuf[lid * 128 + (((kc * 4 + quad) ^ (lid & 7)) * 8)];
    f32x4 V[2];
#pragma unroll
    for (int reg = 0; reg < 4; reg++) { sr[reg] = 0.f; ssr[reg] = 0.f; }
#pragma unroll
    for (int i = 0; i < 2; i++) {
        int ct = w + 4 * i;
        const ushort_t* bp = ohT + (ct * 16 + lid) * 128 + quad * 8;
        f32x4 C = (f32x4){0.f, 0.f, 0.f, 0.f};
#pragma unroll
        for (int kc = 0; kc < 4; kc++) {
            short8 bf = *(const short8*)&bp[kc * 32];
            C = __builtin_amdgcn_mfma_f32_16x16x32_bf16(at[kc], bf, C, 0, 0, 0);
        }
        float bias = ob[ct * 16 + lid];
#pragma unroll
        for (int reg = 0; reg < 4; reg++) {
            float v = gelu_f(C[reg] + bias);
            V[i][reg] = v;
            sr[reg] += v; ssr[reg] += v * v;
        }
    }
#pragma unroll
    for (int st = 1; st <= 8; st <<= 1)
#pragma unroll
        for (int reg = 0; reg < 4; reg++) {
            sr[reg] += __shfl_xor(sr[reg], st);
            ssr[reg] += __shfl_xor(ssr[reg], st);
        }
    if (lid == 0) {
#pragma unroll
        for (int reg = 0; reg < 4; reg++)
            red[w * 16 + quad * 4 + reg] = make_float2(sr[reg], ssr[reg]);
    }
    __syncthreads();
#pragma unroll
    for (int reg = 0; reg < 4; reg++) {
        float S = 0.f, SS = 0.f;
#pragma unroll
        for (int w4 = 0; w4 < 4; w4++) {
            float2 p = red[w4 * 16 + quad * 4 + reg];
            S += p.x; SS += p.y;
        }
        mu2[reg] = S * (1.f / 128.f);
        float var = SS * (1.f / 128.f) - mu2[reg] * mu2[reg];
        rstd2[reg] = rsqrtf(var + 1e-5f);
    }
#pragma unroll
    for (int i = 0; i < 2; i++) {
        int col = (w + 4 * i) * 16 + lid;
        float gv = g3[col], bv = b3[col];
#pragma unroll
        for (int reg = 0; reg < 4; reg++)
            out[(row0 + quad * 4 + reg) * 128 + col] =
                (V[i][reg] - mu2[reg]) * rstd2[reg] * gv + bv;
    }
}

extern "C" void kernel_launch(void* const* d_in, const int* in_sizes, int n_in,
                              void* d_out, int out_size, void* d_ws, size_t ws_size,
                              hipStream_t stream) {
    const float* x      = (const float*)d_in[0];
    const int*   graph  = (const int*)d_in[1];
    const float* a_src0 = (const float*)d_in[3];
    const float* a_dst0 = (const float*)d_in[4];
    const float* a_src1 = (const float*)d_in[6];
    const float* a_dst1 = (const float*)d_in[7];
    const float* ln1_g  = (const float*)d_in[8];
    const float* ln1_b  = (const float*)d_in[9];
    const float* lin_b  = (const float*)d_in[11];
    const float* me_b0  = (const float*)d_in[13];
    const float* me_b1  = (const float*)d_in[15];
    const float* ln2_g  = (const float*)d_in[16];
    const float* ln2_b  = (const float*)d_in[17];
    const float* oh_b   = (const float*)d_in[19];
    const float* ln3_g  = (const float*)d_in[20];
    const float* ln3_b  = (const float*)d_in[21];
    float* out = (float*)d_out;

    float* ws  = (float*)d_ws;
    float*    fA   = ws;                          // 2097152 floats
    float*    fB   = ws + 2097152;                // 2097152 floats
    ushort_t* Ht   = (ushort_t*)(ws + 4194304);   // 2097152 bf16
    float*    e0s  = ws + 5242880;                // 65536
    float*    e0d  = e0s + 65536;                 // 65536
    float*    e1s  = e0d + 65536;                 // 16384
    float*    e1d  = e1s + 16384;                 // 16384
    ushort_t* WT   = (ushort_t*)(e1d + 16384);    // 114688 bf16
    ushort_t* linT = WT;                          // 32768
    ushort_t* meT0 = WT + 32768;                  // 16384
    ushort_t* meT1 = WT + 49152;                  // 16384
    ushort_t* ohT  = WT + 65536;                  // 16384
    ushort_t* W0T  = WT + 81920;                  // 16384
    ushort_t* W1T  = WT + 98304;                  // 16384

    prep_wt<<<448, 256, 0, stream>>>((const float*)d_in[10], (const float*)d_in[12],
                                     (const float*)d_in[14], (const float*)d_in[18],
                                     (const float*)d_in[2], (const float*)d_in[5], WT);
    gemm_mfma<0><<<1024, 256, 0, stream>>>(x, W0T, Ht, a_src0, a_dst0, e0s, e0d);
    gat0_mfma<<<dim3(32, 32), 256, 0, stream>>>(Ht, e0s, e0d, graph, fB);      // m
    gemm_mfma<1><<<1024, 256, 0, stream>>>(fB, W1T, Ht, a_src1, a_dst1, e1s, e1d);
    gat1_mfma<<<dim3(32, 32), 256, 0, stream>>>(Ht, e1s, e1d, graph, fA);      // g1
    head_fused<<<1024, 256, 0, stream>>>(x, fA, ln1_g, ln1_b, linT, lin_b,
                                         meT0, me_b0, meT1, me_b1, ln2_g, ln2_b,
                                         ohT, oh_b, ln3_g, ln3_b, out);
}

// Round 7
// 198.549 us; speedup vs baseline: 2.1653x; 1.0345x over previous
//
#include <hip/hip_runtime.h>
#include <cmath>

// B=32, N=512, IN=128, HID=32, HEADS=4, OUT=128. fp32 in/out; graph int32.
// 4 dispatches: prep_wt ; gemm_mfma0(x,W0T)->Ht0,e0 ;
//   gat0_gemm(Ht0,e0,graph,W1T)->Ht1,e1  [gat0+elu+gemm1 fused, no HBM mid]
//   gat1_head(Ht1,e1,graph,x,...)->out   [gat1+ln1+linear+MLP+ln2+head+ln3]
// 16-row tiles; 1024 blocks; waves split output col-tiles.

typedef unsigned short ushort_t;
typedef __attribute__((ext_vector_type(8))) short short8;
typedef __attribute__((ext_vector_type(4))) float f32x4;

__device__ __forceinline__ float gelu_f(float v) {
    return 0.5f * v * (1.0f + erff(v * 0.70710678118654752f));
}
__device__ __forceinline__ ushort_t f2bf(float x) {      // round-to-nearest-even
    union { float f; unsigned u; } v; v.f = x;
    return (ushort_t)((v.u + 0x7FFFu + ((v.u >> 16) & 1u)) >> 16);
}
__device__ __forceinline__ ushort_t f2bf_t(float x) {    // truncate (hot softmax path)
    union { float f; unsigned u; } v; v.f = x;
    return (ushort_t)(v.u >> 16);
}

// ---- prep: bf16-transpose lin_W(256x128) me_W0 me_W1 oh_W W0 W1 (128x128) ---
__global__ __launch_bounds__(256) void prep_wt(const float* __restrict__ lin_W,
        const float* __restrict__ me_W0, const float* __restrict__ me_W1,
        const float* __restrict__ oh_W, const float* __restrict__ W0,
        const float* __restrict__ W1, ushort_t* __restrict__ WT) {
    int i = blockIdx.x * 256 + threadIdx.x;          // 114688 total
    if (i < 32768)       { int c = i >> 8, k = i & 255;                   WT[i] = f2bf(lin_W[k * 128 + c]); }
    else if (i < 49152)  { int j = i - 32768;  int c = j >> 7, k = j & 127; WT[i] = f2bf(me_W0[k * 128 + c]); }
    else if (i < 65536)  { int j = i - 49152;  int c = j >> 7, k = j & 127; WT[i] = f2bf(me_W1[k * 128 + c]); }
    else if (i < 81920)  { int j = i - 65536;  int c = j >> 7, k = j & 127; WT[i] = f2bf(oh_W[k * 128 + c]); }
    else if (i < 98304)  { int j = i - 81920;  int c = j >> 7, k = j & 127; WT[i] = f2bf(W0[k * 128 + c]); }
    else if (i < 114688) { int j = i - 98304;  int c = j >> 7, k = j & 127; WT[i] = f2bf(W1[k * 128 + c]); }
}

// -- 16-row MFMA gemm: Ht[b][c][m] bf16 = (X@W)^T ; fused e_src/e_dst (4 heads)
__global__ __launch_bounds__(256) void gemm_mfma0(const float* __restrict__ X,
        const ushort_t* __restrict__ WTr, ushort_t* __restrict__ Ht,
        const float* __restrict__ a_s, const float* __restrict__ a_d,
        float* __restrict__ es, float* __restrict__ ed) {
    __shared__ __align__(16) ushort_t abuf[16 * 128];
    __shared__ __align__(16) ushort_t tb[128 * 24];
    __shared__ float2 ered[8 * 16];
    const int tid = threadIdx.x;
    const int row0 = blockIdx.x * 16;
    const int b = row0 >> 9, m0 = row0 & 511;
    const int w = tid >> 6, lane = tid & 63;
    const int quad = lane >> 4, lid = lane & 15;
    {
        int r = tid >> 4, g = tid & 15;
        const float4* src = (const float4*)(X + (row0 + r) * 128 + g * 8);
        float4 a = src[0], bb = src[1];
        short8 p;
        p[0] = (short)f2bf(a.x);  p[1] = (short)f2bf(a.y);
        p[2] = (short)f2bf(a.z);  p[3] = (short)f2bf(a.w);
        p[4] = (short)f2bf(bb.x); p[5] = (short)f2bf(bb.y);
        p[6] = (short)f2bf(bb.z); p[7] = (short)f2bf(bb.w);
        *(short8*)&abuf[r * 128 + ((g ^ (r & 7)) * 8)] = p;
    }
    __syncthreads();
    short8 af[4];
#pragma unroll
    for (int kc = 0; kc < 4; kc++)
        af[kc] = *(const short8*)&abuf[lid * 128 + (((kc * 4 + quad) ^ (lid & 7)) * 8)];
    f32x4 C[2];
#pragma unroll
    for (int i = 0; i < 2; i++) {
        int ct = w + 4 * i;
        const ushort_t* bp = WTr + (ct * 16 + lid) * 128 + quad * 8;
        C[i] = (f32x4){0.f, 0.f, 0.f, 0.f};
#pragma unroll
        for (int kc = 0; kc < 4; kc++) {
            short8 bf = *(const short8*)&bp[kc * 32];
            C[i] = __builtin_amdgcn_mfma_f32_16x16x32_bf16(af[kc], bf, C[i], 0, 0, 0);
        }
    }
#pragma unroll
    for (int i = 0; i < 2; i++) {
        int ct = w + 4 * i, col = ct * 16 + lid;
        float as_c = a_s[col], ad_c = a_d[col];
        float s0[4], d0[4];
#pragma unroll
        for (int r = 0; r < 4; r++) { s0[r] = C[i][r] * as_c; d0[r] = C[i][r] * ad_c; }
#pragma unroll
        for (int st = 1; st <= 8; st <<= 1)
#pragma unroll
            for (int r = 0; r < 4; r++) {
                s0[r] += __shfl_xor(s0[r], st);
                d0[r] += __shfl_xor(d0[r], st);
            }
        if (lid == 0) {
#pragma unroll
            for (int r = 0; r < 4; r++)
                ered[ct * 16 + quad * 4 + r] = make_float2(s0[r], d0[r]);
        }
#pragma unroll
        for (int r = 0; r < 4; r++)
            tb[col * 24 + quad * 4 + r] = f2bf(C[i][r]);
    }
    __syncthreads();
    if (tid < 64) {
        int row = tid & 15, h = tid >> 4;
        float2 pa = ered[(2 * h) * 16 + row], pb = ered[(2 * h + 1) * 16 + row];
        es[(b * 4 + h) * 512 + m0 + row] = pa.x + pb.x;
        ed[(b * 4 + h) * 512 + m0 + row] = pa.y + pb.y;
    }
    {
        int c = tid >> 1, half = tid & 1;
        *(short8*)&Ht[b * 65536 + c * 512 + m0 + half * 8] = *(const short8*)&tb[c * 24 + half * 8];
    }
}

// ---- K2: gat0 (softmax-agg + ELU, regs) -> gemm vs W1T -> Ht1, e1 -----------
__global__ __launch_bounds__(256) void gat0_gemm(const ushort_t* __restrict__ Ht0,
        const float* __restrict__ es0, const float* __restrict__ ed0,
        const int* __restrict__ graph, const ushort_t* __restrict__ W1T,
        const float* __restrict__ a_s, const float* __restrict__ a_d,
        ushort_t* __restrict__ Ht1, float* __restrict__ es1, float* __restrict__ ed1) {
    __shared__ __align__(16) char smem[33024];
    ushort_t* hsb  = (ushort_t*)smem;              // [0,16384)  gat phase
    ushort_t* ps   = (ushort_t*)(smem + 16384);    // [16384,24576) gat
    float*    eds  = (float*)(smem + 24576);       // [24576,32768) gat
    float*    ess  = (float*)(smem + 32768);       // 256B gat
    ushort_t* abuf = (ushort_t*)(smem + 16384);    // gemm phase (over ps)
    ushort_t* tb   = (ushort_t*)(smem + 24576);    // gemm (over eds)
    float2*   ered = (float2*)(smem + 30720);      // gemm
    const int tid = threadIdx.x;
    const int b = blockIdx.y, n0 = blockIdx.x * 16;
    const int lane = tid & 63, wv = tid >> 6;      // wv = head (gat) / col-block (gemm)
    const int quad = lane >> 4, lid = lane & 15;
    const int pn = tid >> 4, pg = (tid >> 1) & 7, ph = tid & 1;
    for (int i = tid; i < 2048; i += 256) eds[i] = ed0[b * 2048 + i];
    if (tid < 64) ess[tid] = es0[b * 2048 + (tid >> 4) * 512 + n0 + (tid & 15)];
    const short8 onesf = {0x3F80, 0x3F80, 0x3F80, 0x3F80, 0x3F80, 0x3F80, 0x3F80, 0x3F80};
    f32x4 acc[2], dsf;
    acc[0] = (f32x4){0.f, 0.f, 0.f, 0.f};
    acc[1] = (f32x4){0.f, 0.f, 0.f, 0.f};
    dsf = (f32x4){0.f, 0.f, 0.f, 0.f};
    for (int mc = 0; mc < 512; mc += 64) {
        __syncthreads();
        {
            const ushort_t* src = Ht0 + b * 65536 + mc;
            for (int u = tid; u < 1024; u += 256) {
                int c = u >> 3, g = u & 7;
                *(short8*)&hsb[c * 64 + ((g ^ (c & 7)) * 8)] = *(const short8*)&src[c * 512 + g * 8];
            }
        }
        {
            int ng = n0 + pn, mbase = mc + pg * 8;
            const int* grow = graph + (b * 512 + ng) * 512 + mbase;
            int4 ga = *(const int4*)grow;
            int4 gb = *(const int4*)(grow + 4);
            int gv[8] = {ga.x, ga.y, ga.z, ga.w, gb.x, gb.y, gb.z, gb.w};
            bool keep[8];
#pragma unroll
            for (int j = 0; j < 8; j++)
                keep[j] = (gv[j] > 0) | ((mbase + j) == ng);
#pragma unroll
            for (int hi = 0; hi < 2; hi++) {
                int hh = ph * 2 + hi;
                float es_v = ess[hh * 16 + pn];
                float4 e0v = *(const float4*)&eds[hh * 512 + mbase];
                float4 e1v = *(const float4*)&eds[hh * 512 + mbase + 4];
                float ev[8] = {e0v.x, e0v.y, e0v.z, e0v.w, e1v.x, e1v.y, e1v.z, e1v.w};
                short8 pk;
#pragma unroll
                for (int j = 0; j < 8; j++) {
                    float e = es_v + ev[j];
                    e = fmaxf(e, 0.2f * e);
                    e = keep[j] ? e : -1e30f;
                    pk[j] = (short)f2bf_t(__expf(e));
                }
                int prow = hh * 16 + pn;
                *(short8*)&ps[prow * 64 + ((pg ^ (prow & 7)) * 8)] = pk;
            }
        }
        __syncthreads();
#pragma unroll
        for (int kc = 0; kc < 2; kc++) {
            const int gsw = ((kc * 4 + quad) ^ (lid & 7)) * 8;
            short8 a = *(const short8*)&ps[(wv * 16 + lid) * 64 + gsw];
            short8 b0f = *(const short8*)&hsb[(wv * 32 + lid) * 64 + gsw];
            short8 b1f = *(const short8*)&hsb[(wv * 32 + 16 + lid) * 64 + gsw];
            acc[0] = __builtin_amdgcn_mfma_f32_16x16x32_bf16(a, b0f, acc[0], 0, 0, 0);
            acc[1] = __builtin_amdgcn_mfma_f32_16x16x32_bf16(a, b1f, acc[1], 0, 0, 0);
            dsf = __builtin_amdgcn_mfma_f32_16x16x32_bf16(a, onesf, dsf, 0, 0, 0);
        }
    }
    __syncthreads();                                // gat LDS reads done; abuf overlay safe
    // ---- m = elu(softmax-agg) -> bf16 A-tile ----
#pragma unroll
    for (int reg = 0; reg < 4; reg++) {
        float inv = 1.0f / dsf[reg];
        int rw = quad * 4 + reg;
#pragma unroll
        for (int ch = 0; ch < 2; ch++) {
            float v = acc[ch][reg] * inv;
            v = v > 0.f ? v : expm1f(v);            // ELU
            int col = wv * 32 + ch * 16 + lid;
            abuf[rw * 128 + (((col >> 3) ^ (rw & 7)) * 8) + (col & 7)] = f2bf(v);
        }
    }
    __syncthreads();
    // ---- gemm vs W1T + fused e1 (1 head) + Ht1 ----
    short8 af[4];
#pragma unroll
    for (int kc = 0; kc < 4; kc++)
        af[kc] = *(const short8*)&abuf[lid * 128 + (((kc * 4 + quad) ^ (lid & 7)) * 8)];
    f32x4 C[2];
#pragma unroll
    for (int i = 0; i < 2; i++) {
        int ct = wv + 4 * i;
        const ushort_t* bp = W1T + (ct * 16 + lid) * 128 + quad * 8;
        C[i] = (f32x4){0.f, 0.f, 0.f, 0.f};
#pragma unroll
        for (int kc = 0; kc < 4; kc++) {
            short8 bf = *(const short8*)&bp[kc * 32];
            C[i] = __builtin_amdgcn_mfma_f32_16x16x32_bf16(af[kc], bf, C[i], 0, 0, 0);
        }
    }
#pragma unroll
    for (int i = 0; i < 2; i++) {
        int ct = wv + 4 * i, col = ct * 16 + lid;
        float as_c = a_s[col], ad_c = a_d[col];
        float s0[4], d0[4];
#pragma unroll
        for (int r = 0; r < 4; r++) { s0[r] = C[i][r] * as_c; d0[r] = C[i][r] * ad_c; }
#pragma unroll
        for (int st = 1; st <= 8; st <<= 1)
#pragma unroll
            for (int r = 0; r < 4; r++) {
                s0[r] += __shfl_xor(s0[r], st);
                d0[r] += __shfl_xor(d0[r], st);
            }
        if (lid == 0) {
#pragma unroll
            for (int r = 0; r < 4; r++)
                ered[ct * 16 + quad * 4 + r] = make_float2(s0[r], d0[r]);
        }
#pragma unroll
        for (int r = 0; r < 4; r++)
            tb[col * 24 + quad * 4 + r] = f2bf(C[i][r]);
    }
    __syncthreads();
    if (tid < 16) {
        float S = 0.f, D = 0.f;
#pragma unroll
        for (int ct = 0; ct < 8; ct++) { float2 p = ered[ct * 16 + tid]; S += p.x; D += p.y; }
        es1[b * 512 + n0 + tid] = S;
        ed1[b * 512 + n0 + tid] = D;
    }
    {
        int c = tid >> 1, half = tid & 1;
        *(short8*)&Ht1[b * 65536 + c * 512 + n0 + half * 8] = *(const short8*)&tb[c * 24 + half * 8];
    }
}

// ---- K3: gat1 (regs) -> ln1(x||G)@lin_W -> MLP -> ln2 -> head -> ln3 -> out -
__global__ __launch_bounds__(256) void gat1_head(const ushort_t* __restrict__ Ht,
        const float* __restrict__ es1, const float* __restrict__ ed1,
        const int* __restrict__ graph, const float* __restrict__ x,
        const float* __restrict__ g1, const float* __restrict__ b1,
        const ushort_t* __restrict__ linT, const float* __restrict__ LB,
        const ushort_t* __restrict__ meT0, const float* __restrict__ B0,
        const ushort_t* __restrict__ meT1, const float* __restrict__ B1,
        const float* __restrict__ g2, const float* __restrict__ b2,
        const ushort_t* __restrict__ ohT, const float* __restrict__ ob,
        const float* __restrict__ g3, const float* __restrict__ b3,
        float* __restrict__ out) {
    __shared__ __align__(16) char smem[25472];
    ushort_t* hsb  = (ushort_t*)smem;              // [0,16384) gat phase
    ushort_t* ps   = (ushort_t*)(smem + 16384);    // 2KB gat
    float*    eds  = (float*)(smem + 18432);       // 2KB gat
    float*    ess  = (float*)(smem + 20480);       // 64B gat
    ushort_t* ybuf = (ushort_t*)smem;              // [0,8192) head (over hsb)
    ushort_t* abuf = (ushort_t*)(smem + 8192);     // 4KB head
    ushort_t* tbuf = (ushort_t*)(smem + 12288);    // 4KB head
    float*    gbuf = (float*)(smem + 16384);       // 8448B head (over ps/eds/ess)
    float2*   red  = (float2*)(smem + 24832);      // 512B
    float2*   mvs  = (float2*)(smem + 25344);      // 128B
    const int tid = threadIdx.x;
    const int b = blockIdx.y, n0 = blockIdx.x * 16;
    const int lane = tid & 63, wv = tid >> 6;
    const int quad = lane >> 4, lid = lane & 15;
    for (int i = tid; i < 512; i += 256) eds[i] = ed1[b * 512 + i];
    if (tid < 16) ess[tid] = es1[b * 512 + n0 + tid];
    const short8 onesf = {0x3F80, 0x3F80, 0x3F80, 0x3F80, 0x3F80, 0x3F80, 0x3F80, 0x3F80};
    f32x4 acc[2], dsf;
    acc[0] = (f32x4){0.f, 0.f, 0.f, 0.f};
    acc[1] = (f32x4){0.f, 0.f, 0.f, 0.f};
    dsf = (f32x4){0.f, 0.f, 0.f, 0.f};
    for (int mc = 0; mc < 512; mc += 64) {
        __syncthreads();
        {
            const ushort_t* src = Ht + b * 65536 + mc;
            for (int u = tid; u < 1024; u += 256) {
                int c = u >> 3, g = u & 7;
                *(short8*)&hsb[c * 64 + ((g ^ (c & 7)) * 8)] = *(const short8*)&src[c * 512 + g * 8];
            }
        }
        if (tid < 128) {
            int pn = tid >> 3, pg = tid & 7;
            int ng = n0 + pn, mbase = mc + pg * 8;
            const int* grow = graph + (b * 512 + ng) * 512 + mbase;
            int4 ga = *(const int4*)grow;
            int4 gb = *(const int4*)(grow + 4);
            int gv[8] = {ga.x, ga.y, ga.z, ga.w, gb.x, gb.y, gb.z, gb.w};
            float4 e0v = *(const float4*)&eds[mbase & 511];
            float4 e1v = *(const float4*)&eds[(mbase & 511) + 4];
            float ev[8] = {e0v.x, e0v.y, e0v.z, e0v.w, e1v.x, e1v.y, e1v.z, e1v.w};
            float es_v = ess[pn];
            short8 pk;
#pragma unroll
            for (int j = 0; j < 8; j++) {
                float e = es_v + ev[j];
                e = fmaxf(e, 0.2f * e);
                e = ((gv[j] > 0) | ((mbase + j) == ng)) ? e : -1e30f;
                pk[j] = (short)f2bf_t(__expf(e));
            }
            *(short8*)&ps[pn * 64 + ((pg ^ (pn & 7)) * 8)] = pk;
        }
        __syncthreads();
#pragma unroll
        for (int kc = 0; kc < 2; kc++) {
            const int gsw = ((kc * 4 + quad) ^ (lid & 7)) * 8;
            short8 a = *(const short8*)&ps[lid * 64 + gsw];
            short8 b0f = *(const short8*)&hsb[(wv * 32 + lid) * 64 + gsw];
            short8 b1f = *(const short8*)&hsb[(wv * 32 + 16 + lid) * 64 + gsw];
            acc[0] = __builtin_amdgcn_mfma_f32_16x16x32_bf16(a, b0f, acc[0], 0, 0, 0);
            acc[1] = __builtin_amdgcn_mfma_f32_16x16x32_bf16(a, b1f, acc[1], 0, 0, 0);
            dsf = __builtin_amdgcn_mfma_f32_16x16x32_bf16(a, onesf, dsf, 0, 0, 0);
        }
    }
    __syncthreads();                                // gat LDS dead
#pragma unroll
    for (int reg = 0; reg < 4; reg++) {
        float inv = 1.0f / dsf[reg];
        int rw = quad * 4 + reg;
#pragma unroll
        for (int ch = 0; ch < 2; ch++)
            gbuf[rw * 132 + wv * 32 + ch * 16 + lid] = acc[ch][reg] * inv;
    }
    __syncthreads();
    // ---- LN1 over concat(x,G); ybuf bf16 ----
    const int r = tid >> 4, c16 = tid & 15;
    const float4* xp = (const float4*)(x + (b * 512 + n0 + r) * 128);
    float4 vv4[4];
    float s = 0.f, ss = 0.f;
#pragma unroll
    for (int i = 0; i < 4; i++) {
        int c4 = c16 * 4 + i;
        float4 v = (c4 < 32) ? xp[c4] : *(const float4*)&gbuf[r * 132 + (c4 - 32) * 4];
        vv4[i] = v;
        s += v.x + v.y + v.z + v.w;
        ss += v.x * v.x + v.y * v.y + v.z * v.z + v.w * v.w;
    }
#pragma unroll
    for (int st = 1; st <= 8; st <<= 1) { s += __shfl_xor(s, st); ss += __shfl_xor(ss, st); }
    if (c16 == 0) {
        float mu = s * (1.f / 256.f);
        float var = ss * (1.f / 256.f) - mu * mu;
        mvs[r] = make_float2(mu, rsqrtf(var + 1e-5f));
    }
    __syncthreads();
    {
        float mu = mvs[r].x, rstd = mvs[r].y;
#pragma unroll
        for (int half = 0; half < 2; half++) {
            int g = c16 * 2 + half, c0 = g * 8;
            float va[8] = {vv4[half * 2].x, vv4[half * 2].y, vv4[half * 2].z, vv4[half * 2].w,
                           vv4[half * 2 + 1].x, vv4[half * 2 + 1].y, vv4[half * 2 + 1].z, vv4[half * 2 + 1].w};
            short8 p;
#pragma unroll
            for (int e = 0; e < 8; e++)
                p[e] = (short)f2bf((va[e] - mu) * rstd * g1[c0 + e] + b1[c0 + e]);
            *(short8*)&ybuf[r * 256 + ((g ^ (r & 7)) * 8)] = p;
        }
    }
    __syncthreads();
    // ---- GEMM1: M2 = y @ lin_W + lin_b ----
    short8 af8[8];
#pragma unroll
    for (int ks = 0; ks < 8; ks++)
        af8[ks] = *(const short8*)&ybuf[lid * 256 + (((ks * 4 + quad) ^ (lid & 7)) * 8)];
    f32x4 M2[2];
#pragma unroll
    for (int i = 0; i < 2; i++) {
        int ct = wv + 4 * i;
        const ushort_t* bp = linT + (ct * 16 + lid) * 256 + quad * 8;
        M2[i] = (f32x4){0.f, 0.f, 0.f, 0.f};
#pragma unroll
        for (int ks = 0; ks < 8; ks++) {
            short8 bf = *(const short8*)&bp[ks * 32];
            M2[i] = __builtin_amdgcn_mfma_f32_16x16x32_bf16(af8[ks], bf, M2[i], 0, 0, 0);
        }
        float bias = LB[ct * 16 + lid];
#pragma unroll
        for (int reg = 0; reg < 4; reg++) M2[i][reg] += bias;
        int col = ct * 16 + lid, g = col >> 3, pos = col & 7;
#pragma unroll
        for (int reg = 0; reg < 4; reg++) {
            int rw = quad * 4 + reg;
            abuf[rw * 128 + ((g ^ (rw & 7)) * 8) + pos] = f2bf(M2[i][reg]);
        }
    }
    __syncthreads();
    // ---- T = gelu(m2 @ me_W0 + b0) ----
    short8 at[4];
#pragma unroll
    for (int kc = 0; kc < 4; kc++)
        at[kc] = *(const short8*)&abuf[lid * 128 + (((kc * 4 + quad) ^ (lid & 7)) * 8)];
#pragma unroll
    for (int i = 0; i < 2; i++) {
        int ct = wv + 4 * i;
        const ushort_t* bp = meT0 + (ct * 16 + lid) * 128 + quad * 8;
        f32x4 C = (f32x4){0.f, 0.f, 0.f, 0.f};
#pragma unroll
        for (int kc = 0; kc < 4; kc++) {
            short8 bf = *(const short8*)&bp[kc * 32];
            C = __builtin_amdgcn_mfma_f32_16x16x32_bf16(at[kc], bf, C, 0, 0, 0);
        }
        int col = ct * 16 + lid, g = col >> 3, pos = col & 7;
        float bias = B0[col];
#pragma unroll
        for (int reg = 0; reg < 4; reg++) {
            int rw = quad * 4 + reg;
            tbuf[rw * 128 + ((g ^ (rw & 7)) * 8) + pos] = f2bf(gelu_f(C[reg] + bias));
        }
    }
    __syncthreads();
    // ---- enc = T @ me_W1 + b1 ; R = m2 + enc ; ln2 ----
#pragma unroll
    for (int kc = 0; kc < 4; kc++)
        at[kc] = *(const short8*)&tbuf[lid * 128 + (((kc * 4 + quad) ^ (lid & 7)) * 8)];
    f32x4 R[2];
    float sr[4] = {0.f, 0.f, 0.f, 0.f}, ssr[4] = {0.f, 0.f, 0.f, 0.f};
#pragma unroll
    for (int i = 0; i < 2; i++) {
        int ct = wv + 4 * i;
        const ushort_t* bp = meT1 + (ct * 16 + lid) * 128 + quad * 8;
        f32x4 C = (f32x4){0.f, 0.f, 0.f, 0.f};
#pragma unroll
        for (int kc = 0; kc < 4; kc++) {
            short8 bf = *(const short8*)&bp[kc * 32];
            C = __builtin_amdgcn_mfma_f32_16x16x32_bf16(at[kc], bf, C, 0, 0, 0);
        }
        float bias = B1[ct * 16 + lid];
#pragma unroll
        for (int reg = 0; reg < 4; reg++) {
            float v = M2[i][reg] + C[reg] + bias;
            R[i][reg] = v;
            sr[reg] += v; ssr[reg] += v * v;
        }
    }
#pragma unroll
    for (int st = 1; st <= 8; st <<= 1)
#pragma unroll
        for (int reg = 0; reg < 4; reg++) {
            sr[reg] += __shfl_xor(sr[reg], st);
            ssr[reg] += __shfl_xor(ssr[reg], st);
        }
    if (lid == 0) {
#pragma unroll
        for (int reg = 0; reg < 4; reg++)
            red[wv * 16 + quad * 4 + reg] = make_float2(sr[reg], ssr[reg]);
    }
    __syncthreads();
    float mu2[4], rstd2[4];
#pragma unroll
    for (int reg = 0; reg < 4; reg++) {
        float S = 0.f, SS = 0.f;
#pragma unroll
        for (int w4 = 0; w4 < 4; w4++) {
            float2 p = red[w4 * 16 + quad * 4 + reg];
            S += p.x; SS += p.y;
        }
        mu2[reg] = S * (1.f / 128.f);
        float var = SS * (1.f / 128.f) - mu2[reg] * mu2[reg];
        rstd2[reg] = rsqrtf(var + 1e-5f);
    }
#pragma unroll
    for (int i = 0; i < 2; i++) {
        int col = (wv + 4 * i) * 16 + lid, g = col >> 3, pos = col & 7;
        float gv = g2[col], bv = b2[col];
#pragma unroll
        for (int reg = 0; reg < 4; reg++) {
            int rw = quad * 4 + reg;
            float v = (R[i][reg] - mu2[reg]) * rstd2[reg] * gv + bv;
            tbuf[rw * 128 + ((g ^ (rw & 7)) * 8) + pos] = f2bf(v);
        }
    }
    __syncthreads();
    // ---- V = gelu(r @ oh_W + ob) ; ln3 ; store ----
#pragma unroll
    for (int kc = 0; kc < 4; kc++)
        at[kc] = *(const short8*)&tbuf[lid * 128 + (((kc * 4 + quad) ^ (lid & 7)) * 8)];
    f32x4 V[2];
#pragma unroll
    for (int reg = 0; reg < 4; reg++) { sr[reg] = 0.f; ssr[reg] = 0.f; }
#pragma unroll
    for (int i = 0; i < 2; i++) {
        int ct = wv + 4 * i;
        const ushort_t* bp = ohT + (ct * 16 + lid) * 128 + quad * 8;
        f32x4 C = (f32x4){0.f, 0.f, 0.f, 0.f};
#pragma unroll
        for (int kc = 0; kc < 4; kc++) {
            short8 bf = *(const short8*)&bp[kc * 32];
            C = __builtin_amdgcn_mfma_f32_16x16x32_bf16(at[kc], bf, C, 0, 0, 0);
        }
        float bias = ob[ct * 16 + lid];
#pragma unroll
        for (int reg = 0; reg < 4; reg++) {
            float v = gelu_f(C[reg] + bias);
            V[i][reg] = v;
            sr[reg] += v; ssr[reg] += v * v;
        }
    }
#pragma unroll
    for (int st = 1; st <= 8; st <<= 1)
#pragma unroll
        for (int reg = 0; reg < 4; reg++) {
            sr[reg] += __shfl_xor(sr[reg], st);
            ssr[reg] += __shfl_xor(ssr[reg], st);
        }
    if (lid == 0) {
#pragma unroll
        for (int reg = 0; reg < 4; reg++)
            red[wv * 16 + quad * 4 + reg] = make_float2(sr[reg], ssr[reg]);
    }
    __syncthreads();
#pragma unroll
    for (int reg = 0; reg < 4; reg++) {
        float S = 0.f, SS = 0.f;
#pragma unroll
        for (int w4 = 0; w4 < 4; w4++) {
            float2 p = red[w4 * 16 + quad * 4 + reg];
            S += p.x; SS += p.y;
        }
        mu2[reg] = S * (1.f / 128.f);
        float var = SS * (1.f / 128.f) - mu2[reg] * mu2[reg];
        rstd2[reg] = rsqrtf(var + 1e-5f);
    }
#pragma unroll
    for (int i = 0; i < 2; i++) {
        int col = (wv + 4 * i) * 16 + lid;
        float gv = g3[col], bv = b3[col];
#pragma unroll
        for (int reg = 0; reg < 4; reg++)
            out[(b * 512 + n0 + quad * 4 + reg) * 128 + col] =
                (V[i][reg] - mu2[reg]) * rstd2[reg] * gv + bv;
    }
}

extern "C" void kernel_launch(void* const* d_in, const int* in_sizes, int n_in,
                              void* d_out, int out_size, void* d_ws, size_t ws_size,
                              hipStream_t stream) {
    const float* x      = (const float*)d_in[0];
    const int*   graph  = (const int*)d_in[1];
    const float* a_src0 = (const float*)d_in[3];
    const float* a_dst0 = (const float*)d_in[4];
    const float* a_src1 = (const float*)d_in[6];
    const float* a_dst1 = (const float*)d_in[7];
    float* out = (float*)d_out;

    float* ws  = (float*)d_ws;
    ushort_t* Ht0  = (ushort_t*)ws;               // 2097152 bf16 (1048576 floats)
    ushort_t* Ht1  = Ht0 + 2097152;               // 2097152 bf16
    float*    e0s  = ws + 2097152;                // 65536
    float*    e0d  = e0s + 65536;                 // 65536
    float*    e1s  = e0d + 65536;                 // 16384
    float*    e1d  = e1s + 16384;                 // 16384
    ushort_t* WT   = (ushort_t*)(e1d + 16384);    // 114688 bf16
    ushort_t* linT = WT;                          // 32768
    ushort_t* meT0 = WT + 32768;                  // 16384
    ushort_t* meT1 = WT + 49152;                  // 16384
    ushort_t* ohT  = WT + 65536;                  // 16384
    ushort_t* W0T  = WT + 81920;                  // 16384
    ushort_t* W1T  = WT + 98304;                  // 16384

    prep_wt<<<448, 256, 0, stream>>>((const float*)d_in[10], (const float*)d_in[12],
                                     (const float*)d_in[14], (const float*)d_in[18],
                                     (const float*)d_in[2], (const float*)d_in[5], WT);
    gemm_mfma0<<<1024, 256, 0, stream>>>(x, W0T, Ht0, a_src0, a_dst0, e0s, e0d);
    gat0_gemm<<<dim3(32, 32), 256, 0, stream>>>(Ht0, e0s, e0d, graph, W1T,
                                                a_src1, a_dst1, Ht1, e1s, e1d);
    gat1_head<<<dim3(32, 32), 256, 0, stream>>>(Ht1, e1s, e1d, graph, x,
                                                (const float*)d_in[8], (const float*)d_in[9],
                                                linT, (const float*)d_in[11],
                                                meT0, (const float*)d_in[13],
                                                meT1, (const float*)d_in[15],
                                                (const float*)d_in[16], (const float*)d_in[17],
                                                ohT, (const float*)d_in[19],
                                                (const float*)d_in[20], (const float*)d_in[21],
                                                out);
}